// Round 2
// baseline (1732.793 us; speedup 1.0000x reference)
//
#include <hip/hip_runtime.h>
#include <math.h>

#define TPB 256
#define P_BLOCKS 128
#define MAXB 1600   // >= ceil(100000/64)=1563

// ---------------- bucketed histogram: counts[bin*P + blk] ----------------
__global__ void __launch_bounds__(256) k_bhist(const int* __restrict__ dst,
                                               int* __restrict__ counts, int E, int B) {
  __shared__ int h[MAXB];
  int t = threadIdx.x, blk = blockIdx.x;
  for (int i = t; i < B; i += TPB) h[i] = 0;
  __syncthreads();
  int chunk = (E + P_BLOCKS - 1) / P_BLOCKS;
  int s = blk * chunk, e = min(E, s + chunk);
  for (int i = s + t; i < e; i += TPB) atomicAdd(&h[dst[i] >> 6], 1);
  __syncthreads();
  for (int i = t; i < B; i += TPB) counts[i * P_BLOCKS + blk] = h[i];
}

// ---------------- scan (1024 items/block) ----------------
__global__ void k_scan_block(const int* __restrict__ deg, int* __restrict__ offs,
                             int* __restrict__ bsums, int n) {
  __shared__ int lds[256];
  int t = threadIdx.x, b = blockIdx.x;
  int base = b * 1024 + t * 4;
  int v0 = (base + 0 < n) ? deg[base + 0] : 0;
  int v1 = (base + 1 < n) ? deg[base + 1] : 0;
  int v2 = (base + 2 < n) ? deg[base + 2] : 0;
  int v3 = (base + 3 < n) ? deg[base + 3] : 0;
  int s = v0 + v1 + v2 + v3;
  lds[t] = s;
  __syncthreads();
  int acc = s;
  for (int off = 1; off < 256; off <<= 1) {
    int x = (t >= off) ? lds[t - off] : 0;
    __syncthreads();
    acc += x;
    lds[t] = acc;
    __syncthreads();
  }
  int excl = acc - s;
  if (base + 0 < n) offs[base + 0] = excl;
  if (base + 1 < n) offs[base + 1] = excl + v0;
  if (base + 2 < n) offs[base + 2] = excl + v0 + v1;
  if (base + 3 < n) offs[base + 3] = excl + v0 + v1 + v2;
  if (t == 255) bsums[b] = acc;
}

__global__ void k_scan_mid(int* __restrict__ bsums, int nb) {
  __shared__ int lds[256];
  int t = threadIdx.x;
  int v = (t < nb) ? bsums[t] : 0;
  lds[t] = v;
  __syncthreads();
  int acc = v;
  for (int off = 1; off < 256; off <<= 1) {
    int x = (t >= off) ? lds[t - off] : 0;
    __syncthreads();
    acc += x;
    lds[t] = acc;
    __syncthreads();
  }
  if (t < nb) bsums[t] = acc - v;  // exclusive
}

__global__ void k_scan_add(int* __restrict__ offs, const int* __restrict__ bsums,
                           int n, int total) {
  int t = threadIdx.x, b = blockIdx.x;
  int add = bsums[b];
  int base = b * 1024 + t * 4;
#pragma unroll
  for (int j = 0; j < 4; ++j)
    if (base + j < n) offs[base + j] += add;
  if (b == 0 && t == 0) offs[n] = total;
}

// ---------------- fill: atomic-free (LDS cursors), streaming bucket appends ----------------
__global__ void __launch_bounds__(256) k_bfill(const int* __restrict__ src,
                                               const int* __restrict__ dst,
                                               const float* __restrict__ attr,
                                               const int* __restrict__ offs,
                                               int2* __restrict__ ebuf, int E, int B) {
  __shared__ int cur[MAXB];
  int t = threadIdx.x, blk = blockIdx.x;
  for (int i = t; i < B; i += TPB) cur[i] = offs[i * P_BLOCKS + blk];
  __syncthreads();
  int chunk = (E + P_BLOCKS - 1) / P_BLOCKS;
  int s = blk * chunk, e = min(E, s + chunk);
  for (int i = s + t; i < e; i += TPB) {
    int d = dst[i];
    int bin = d >> 6;
    int pos = atomicAdd(&cur[bin], 1);
    ebuf[pos] = make_int2((src[i] << 6) | (d & 63), __float_as_int(attr[i]));
  }
}

// ---------------- layer-1 aggregation: one bucket/block, LDS accum 64x9 ----------------
__global__ void __launch_bounds__(256) k_bagg1(
    const float* __restrict__ x, const int2* __restrict__ ebuf,
    const int* __restrict__ offs, const float* __restrict__ We1,
    const float* __restrict__ be1, float* __restrict__ u1, int N) {
  __shared__ float acc[64 * 9];
  int t = threadIdx.x, bkt = blockIdx.x;
  for (int i = t; i < 576; i += TPB) acc[i] = 0.f;
  float we[9], be[9];
#pragma unroll
  for (int f = 0; f < 9; ++f) { we[f] = We1[f]; be[f] = be1[f]; }
  __syncthreads();
  int s = offs[bkt * P_BLOCKS], e = offs[(bkt + 1) * P_BLOCKS];
  for (int i = s + t; i < e; i += TPB) {
    int2 p = ebuf[i];
    int srcn = p.x >> 6, loc = p.x & 63;
    float a = __int_as_float(p.y);
#pragma unroll
    for (int f = 0; f < 9; ++f) {
      float m = fmaxf(x[srcn * 9 + f] + fmaf(a, we[f], be[f]), 0.f);
      atomicAdd(&acc[loc * 9 + f], m);
    }
  }
  __syncthreads();
  int n0 = bkt << 6;
  for (int i = t; i < 576; i += TPB) {
    int r = i / 9, c = i - r * 9;
    int n = n0 + r;
    if (n < N) u1[n * 9 + c] = x[n * 9 + c] + acc[i];
  }
}

// ---------------- layer-2 aggregation: one bucket/block, LDS accum 64x64 ----------------
__global__ void __launch_bounds__(256) k_bagg2(
    const float* __restrict__ h1, const int2* __restrict__ ebuf,
    const int* __restrict__ offs, const float* __restrict__ We2,
    const float* __restrict__ be2, float* __restrict__ u2, int N) {
  __shared__ float acc[64 * 64];
  int t = threadIdx.x, bkt = blockIdx.x;
  int f = t & 63, w = t >> 6;  // lane feature, wave id
  for (int i = t; i < 4096; i += TPB) acc[i] = 0.f;
  float we = We2[f], be = be2[f];
  __syncthreads();
  int s = offs[bkt * P_BLOCKS], e = offs[(bkt + 1) * P_BLOCKS];
  // 4 waves x 4-edge groups: 4 independent gathers in flight per wave
  for (int base = s + 4 * w; base < e; base += 16) {
    int m = e - base;  // >=1
    int2 p0 = ebuf[base];
    int2 p1 = (m > 1) ? ebuf[base + 1] : p0;
    int2 p2 = (m > 2) ? ebuf[base + 2] : p0;
    int2 p3 = (m > 3) ? ebuf[base + 3] : p0;
    float v0 = h1[(p0.x >> 6) * 64 + f];
    float v1 = h1[(p1.x >> 6) * 64 + f];
    float v2 = h1[(p2.x >> 6) * 64 + f];
    float v3 = h1[(p3.x >> 6) * 64 + f];
    atomicAdd(&acc[(p0.x & 63) * 64 + f],
              fmaxf(v0 + fmaf(__int_as_float(p0.y), we, be), 0.f));
    if (m > 1) atomicAdd(&acc[(p1.x & 63) * 64 + f],
                         fmaxf(v1 + fmaf(__int_as_float(p1.y), we, be), 0.f));
    if (m > 2) atomicAdd(&acc[(p2.x & 63) * 64 + f],
                         fmaxf(v2 + fmaf(__int_as_float(p2.y), we, be), 0.f));
    if (m > 3) atomicAdd(&acc[(p3.x & 63) * 64 + f],
                         fmaxf(v3 + fmaf(__int_as_float(p3.y), we, be), 0.f));
  }
  __syncthreads();
  int n0 = bkt << 6;
  for (int r = w; r < 64; r += 4) {
    int n = n0 + r;
    if (n < N) u2[n * 64 + f] = h1[n * 64 + f] + acc[r * 64 + f];
  }
}

// ---------------- 2-layer MLP: relu(relu(u@Wa+ba)@Wb+bb), tile 64 nodes ----------------
template <int KIN>
__global__ void __launch_bounds__(256) k_mlp(
    const float* __restrict__ uin, const float* __restrict__ Wa,
    const float* __restrict__ ba, const float* __restrict__ Wb,
    const float* __restrict__ bb, float* __restrict__ hout, int N) {
  constexpr int US = (KIN == 64) ? 65 : KIN;
  __shared__ float ls_in[64 * US];
  __shared__ float ls_z[64 * 65];
  __shared__ float ls_w[64 * 64];
  __shared__ float ls_b[128];
  const int t = threadIdx.x;
  const int n0 = blockIdx.x * 64;

  for (int i = t; i < 64 * KIN; i += TPB) {
    int r = i / KIN, c = i % KIN;
    int g = n0 + r;
    ls_in[r * US + c] = (g < N) ? uin[g * KIN + c] : 0.f;
  }
  for (int i = t; i < KIN * 64; i += TPB) ls_w[i] = Wa[i];
  if (t < 64) { ls_b[t] = ba[t]; ls_b[64 + t] = bb[t]; }
  __syncthreads();

  const int of = (t & 15) * 4, nb = (t >> 4) * 4;
  float acc[4][4];
#pragma unroll
  for (int i = 0; i < 4; ++i)
#pragma unroll
    for (int j = 0; j < 4; ++j) acc[i][j] = 0.f;

  for (int k = 0; k < KIN; ++k) {
    float4 w = *(const float4*)&ls_w[k * 64 + of];
#pragma unroll
    for (int ni = 0; ni < 4; ++ni) {
      float uv = ls_in[(nb + ni) * US + k];
      acc[ni][0] += uv * w.x; acc[ni][1] += uv * w.y;
      acc[ni][2] += uv * w.z; acc[ni][3] += uv * w.w;
    }
  }
#pragma unroll
  for (int ni = 0; ni < 4; ++ni)
#pragma unroll
    for (int oi = 0; oi < 4; ++oi)
      ls_z[(nb + ni) * 65 + of + oi] = fmaxf(acc[ni][oi] + ls_b[of + oi], 0.f);
  __syncthreads();
  for (int i = t; i < 4096; i += TPB) ls_w[i] = Wb[i];
  __syncthreads();

#pragma unroll
  for (int i = 0; i < 4; ++i)
#pragma unroll
    for (int j = 0; j < 4; ++j) acc[i][j] = 0.f;
  for (int k = 0; k < 64; ++k) {
    float4 w = *(const float4*)&ls_w[k * 64 + of];
#pragma unroll
    for (int ni = 0; ni < 4; ++ni) {
      float zv = ls_z[(nb + ni) * 65 + k];
      acc[ni][0] += zv * w.x; acc[ni][1] += zv * w.y;
      acc[ni][2] += zv * w.z; acc[ni][3] += zv * w.w;
    }
  }
#pragma unroll
  for (int ni = 0; ni < 4; ++ni) {
    int n = n0 + nb + ni;
    if (n < N) {
      float4 o;
      o.x = fmaxf(acc[ni][0] + ls_b[64 + of + 0], 0.f);
      o.y = fmaxf(acc[ni][1] + ls_b[64 + of + 1], 0.f);
      o.z = fmaxf(acc[ni][2] + ls_b[64 + of + 2], 0.f);
      o.w = fmaxf(acc[ni][3] + ls_b[64 + of + 3], 0.f);
      *(float4*)&hout[n * 64 + of] = o;
    }
  }
}

// ---------------- Readout ----------------
__global__ void __launch_bounds__(256) k_readout(
    const float* __restrict__ h2, const float* __restrict__ Wr1,
    const float* __restrict__ br1, const float* __restrict__ Wr2,
    const float* __restrict__ br2, const int* __restrict__ tmask,
    float* __restrict__ pi, int N) {
  __shared__ float ls_h[32 * 65];
  __shared__ float ls_w[64 * 32];
  __shared__ float ls_w2[32];
  __shared__ float ls_b1[32];
  int t = threadIdx.x;
  int n0 = blockIdx.x * 32;
  for (int i = t; i < 32 * 64; i += TPB) {
    int r = i >> 6, c = i & 63;
    int g = n0 + r;
    ls_h[r * 65 + c] = (g < N) ? h2[g * 64 + c] : 0.f;
  }
  for (int i = t; i < 2048; i += TPB) ls_w[i] = Wr1[i];
  if (t < 32) { ls_w2[t] = Wr2[t]; ls_b1[t] = br1[t]; }
  __syncthreads();
  int of = t & 31, q = t >> 5;
  float b2 = br2[0];
#pragma unroll
  for (int j = 0; j < 4; ++j) {
    int n = q * 4 + j;
    float a = 0.f;
    for (int k = 0; k < 64; ++k) a += ls_h[n * 65 + k] * ls_w[k * 32 + of];
    float r = fmaxf(a + ls_b1[of], 0.f) * ls_w2[of];
    for (int s = 16; s > 0; s >>= 1) r += __shfl_down(r, s, 32);
    if (of == 0) {
      int g = n0 + n;
      if (g < N) {
        float sg = 1.f / (1.f + expf(-(r + b2)));
        pi[g] = sg * (1.f - (float)tmask[g]);
      }
    }
  }
}

// ---------------- Group sums (batch sorted) ----------------
__global__ void k_grpsum(const float* __restrict__ pi, const float* __restrict__ c_cost,
                         const int* __restrict__ batch, float* __restrict__ exp_tot, int N) {
  __shared__ float lsf[256];
  __shared__ int lsi[256];
  int t = threadIdx.x;
  int i = blockIdx.x * TPB + t;
  bool valid = i < N;
  int g = valid ? batch[i] : 0;
  float v = valid ? pi[i] * c_cost[i] : 0.f;
  lsi[t] = valid ? g : 0x7fffffff;
  __syncthreads();
  for (int s = 128; s > 0; s >>= 1) { if (t < s) lsi[t] = min(lsi[t], lsi[t + s]); __syncthreads(); }
  int gmin = lsi[0];
  __syncthreads();
  lsi[t] = valid ? g : -1;
  __syncthreads();
  for (int s = 128; s > 0; s >>= 1) { if (t < s) lsi[t] = max(lsi[t], lsi[t + s]); __syncthreads(); }
  int gmax = lsi[0];
  __syncthreads();
  for (int gg = gmin; gg <= gmax; ++gg) {
    lsf[t] = (valid && g == gg) ? v : 0.f;
    __syncthreads();
    for (int s = 128; s > 0; s >>= 1) { if (t < s) lsf[t] += lsf[t + s]; __syncthreads(); }
    if (t == 0) atomicAdd(&exp_tot[gg], lsf[0]);
    __syncthreads();
  }
}

__global__ void k_final(const float* __restrict__ pi, const int* __restrict__ batch,
                        const float* __restrict__ B_total, const float* __restrict__ exp_tot,
                        float* __restrict__ out, int N) {
  int i = blockIdx.x * TPB + threadIdx.x;
  if (i < N) {
    int g = batch[i];
    float ratio = fminf(B_total[g] / (exp_tot[g] + 1e-12f), 1.f);
    out[i] = pi[i] * ratio;
  }
}

extern "C" void kernel_launch(void* const* d_in, const int* in_sizes, int n_in,
                              void* d_out, int out_size, void* d_ws, size_t ws_size,
                              hipStream_t stream) {
  const float* x     = (const float*)d_in[0];
  const int*   ei    = (const int*)d_in[1];
  const float* eattr = (const float*)d_in[2];
  const int*   batch = (const int*)d_in[3];
  const float* Btot  = (const float*)d_in[4];
  const int*   tmask = (const int*)d_in[5];
  const float* ccost = (const float*)d_in[6];
  const float* We1 = (const float*)d_in[7],  *be1 = (const float*)d_in[8];
  const float* W1a = (const float*)d_in[9],  *b1a = (const float*)d_in[10];
  const float* W1b = (const float*)d_in[11], *b1b = (const float*)d_in[12];
  const float* We2 = (const float*)d_in[13], *be2 = (const float*)d_in[14];
  const float* W2a = (const float*)d_in[15], *b2a = (const float*)d_in[16];
  const float* W2b = (const float*)d_in[17], *b2b = (const float*)d_in[18];
  const float* Wr1 = (const float*)d_in[19], *br1 = (const float*)d_in[20];
  const float* Wr2 = (const float*)d_in[21], *br2 = (const float*)d_in[22];
  float* out = (float*)d_out;

  const int N = in_sizes[0] / 9;
  const int E = in_sizes[2];
  const int G = in_sizes[4];
  const int* src = ei;
  const int* dst = ei + E;
  const int B = (N + 63) >> 6;            // buckets of 64 nodes
  const int nscan = B * P_BLOCKS;         // flat (bin,block) count array

  // workspace carve-up (4-byte elements)
  size_t cur = 0;
  auto alloc = [&](size_t elems) { size_t r = cur; cur += elems; cur = (cur + 63) & ~(size_t)63; return r; };
  char* wsb = (char*)d_ws;
  size_t o_exp    = alloc(G);             // must be zeroed
  size_t o_counts = alloc(nscan);
  size_t o_offs   = alloc(nscan + 1);
  size_t o_bsums  = alloc(256);
  size_t o_ebuf   = alloc(2 * (size_t)E); // int2
  size_t o_u1     = alloc((size_t)N * 9);
  size_t o_h1     = alloc((size_t)N * 64);
  size_t o_u2     = alloc((size_t)N * 64);
  size_t o_pi     = alloc(N);
  (void)ws_size;

  float* exp_t  = (float*)wsb + o_exp;
  int*   counts = (int*)wsb + o_counts;
  int*   offs   = (int*)wsb + o_offs;
  int*   bsums  = (int*)wsb + o_bsums;
  int2*  ebuf   = (int2*)((int*)wsb + o_ebuf);
  float* u1     = (float*)wsb + o_u1;
  float* h1     = (float*)wsb + o_h1;
  float* u2     = (float*)wsb + o_u2;
  float* pi     = (float*)wsb + o_pi;

  hipMemsetAsync(exp_t, 0, (size_t)G * 4, stream);

  const int nb = (nscan + 1023) / 1024;   // 196 for N=100k

  k_bhist<<<P_BLOCKS, TPB, 0, stream>>>(dst, counts, E, B);
  k_scan_block<<<nb, TPB, 0, stream>>>(counts, offs, bsums, nscan);
  k_scan_mid<<<1, 256, 0, stream>>>(bsums, nb);
  k_scan_add<<<nb, TPB, 0, stream>>>(offs, bsums, nscan, E);
  k_bfill<<<P_BLOCKS, TPB, 0, stream>>>(src, dst, eattr, offs, ebuf, E, B);

  k_bagg1<<<B, TPB, 0, stream>>>(x, ebuf, offs, We1, be1, u1, N);
  k_mlp<9><<<(N + 63) / 64, TPB, 0, stream>>>(u1, W1a, b1a, W1b, b1b, h1, N);

  k_bagg2<<<B, TPB, 0, stream>>>(h1, ebuf, offs, We2, be2, u2, N);
  k_mlp<64><<<(N + 63) / 64, TPB, 0, stream>>>(u2, W2a, b2a, W2b, b2b, u2, N);

  k_readout<<<(N + 31) / 32, TPB, 0, stream>>>(u2, Wr1, br1, Wr2, br2, tmask, pi, N);
  k_grpsum<<<(N + TPB - 1) / TPB, TPB, 0, stream>>>(pi, ccost, batch, exp_t, N);
  k_final<<<(N + TPB - 1) / TPB, TPB, 0, stream>>>(pi, batch, Btot, exp_t, out, N);
}

// Round 3
// 560.423 us; speedup vs baseline: 3.0919x; 3.0919x over previous
//
#include <hip/hip_runtime.h>
#include <math.h>

#define TPB 256
#define P_BLOCKS 128
#define MAXB 1600   // >= ceil(100000/64)=1563

// ---------------- bucketed histogram: counts[bin*P + blk] ----------------
__global__ void __launch_bounds__(256) k_bhist(const int* __restrict__ dst,
                                               int* __restrict__ counts, int E, int B) {
  __shared__ int h[MAXB];
  int t = threadIdx.x, blk = blockIdx.x;
  for (int i = t; i < B; i += TPB) h[i] = 0;
  __syncthreads();
  int chunk = (E + P_BLOCKS - 1) / P_BLOCKS;
  int s = blk * chunk, e = min(E, s + chunk);
  for (int i = s + t; i < e; i += TPB) atomicAdd(&h[dst[i] >> 6], 1);
  __syncthreads();
  for (int i = t; i < B; i += TPB) counts[i * P_BLOCKS + blk] = h[i];
}

// ---------------- scan (1024 items/block) ----------------
__global__ void k_scan_block(const int* __restrict__ deg, int* __restrict__ offs,
                             int* __restrict__ bsums, int n) {
  __shared__ int lds[256];
  int t = threadIdx.x, b = blockIdx.x;
  int base = b * 1024 + t * 4;
  int v0 = (base + 0 < n) ? deg[base + 0] : 0;
  int v1 = (base + 1 < n) ? deg[base + 1] : 0;
  int v2 = (base + 2 < n) ? deg[base + 2] : 0;
  int v3 = (base + 3 < n) ? deg[base + 3] : 0;
  int s = v0 + v1 + v2 + v3;
  lds[t] = s;
  __syncthreads();
  int acc = s;
  for (int off = 1; off < 256; off <<= 1) {
    int x = (t >= off) ? lds[t - off] : 0;
    __syncthreads();
    acc += x;
    lds[t] = acc;
    __syncthreads();
  }
  int excl = acc - s;
  if (base + 0 < n) offs[base + 0] = excl;
  if (base + 1 < n) offs[base + 1] = excl + v0;
  if (base + 2 < n) offs[base + 2] = excl + v0 + v1;
  if (base + 3 < n) offs[base + 3] = excl + v0 + v1 + v2;
  if (t == 255) bsums[b] = acc;
}

__global__ void k_scan_mid(int* __restrict__ bsums, int nb) {
  __shared__ int lds[256];
  int t = threadIdx.x;
  int v = (t < nb) ? bsums[t] : 0;
  lds[t] = v;
  __syncthreads();
  int acc = v;
  for (int off = 1; off < 256; off <<= 1) {
    int x = (t >= off) ? lds[t - off] : 0;
    __syncthreads();
    acc += x;
    lds[t] = acc;
    __syncthreads();
  }
  if (t < nb) bsums[t] = acc - v;  // exclusive
}

__global__ void k_scan_add(int* __restrict__ offs, const int* __restrict__ bsums,
                           int n, int total) {
  int t = threadIdx.x, b = blockIdx.x;
  int add = bsums[b];
  int base = b * 1024 + t * 4;
#pragma unroll
  for (int j = 0; j < 4; ++j)
    if (base + j < n) offs[base + j] += add;
  if (b == 0 && t == 0) offs[n] = total;
}

// ---------------- fill: atomic-free (LDS cursors), streaming bucket appends ----------------
__global__ void __launch_bounds__(256) k_bfill(const int* __restrict__ src,
                                               const int* __restrict__ dst,
                                               const float* __restrict__ attr,
                                               const int* __restrict__ offs,
                                               int2* __restrict__ ebuf, int E, int B) {
  __shared__ int cur[MAXB];
  int t = threadIdx.x, blk = blockIdx.x;
  for (int i = t; i < B; i += TPB) cur[i] = offs[i * P_BLOCKS + blk];
  __syncthreads();
  int chunk = (E + P_BLOCKS - 1) / P_BLOCKS;
  int s = blk * chunk, e = min(E, s + chunk);
  for (int i = s + t; i < e; i += TPB) {
    int d = dst[i];
    int bin = d >> 6;
    int pos = atomicAdd(&cur[bin], 1);
    ebuf[pos] = make_int2((src[i] << 6) | (d & 63), __float_as_int(attr[i]));
  }
}

// ---------------- per-bucket counting sort -> dst-sorted csr + node offsets ----------------
__global__ void __launch_bounds__(256) k_bsort(const int2* __restrict__ ebuf,
                                               const int* __restrict__ offs,
                                               int2* __restrict__ csr,
                                               int* __restrict__ noffs,
                                               int N, int E) {
  __shared__ int hist[64];
  __shared__ int cursor[64];
  int t = threadIdx.x, bkt = blockIdx.x;
  if (t < 64) hist[t] = 0;
  __syncthreads();
  int s = offs[bkt * P_BLOCKS], e = offs[(bkt + 1) * P_BLOCKS];
  for (int i = s + t; i < e; i += TPB) atomicAdd(&hist[ebuf[i].x & 63], 1);
  __syncthreads();
  if (t < 64) {
    int v = hist[t];
    int sc = v;
#pragma unroll
    for (int d = 1; d < 64; d <<= 1) {
      int o = __shfl_up(sc, d, 64);
      if (t >= d) sc += o;
    }
    int base = s + sc - v;  // exclusive
    cursor[t] = base;
    int n = (bkt << 6) + t;
    if (n < N) noffs[n] = base;
  }
  if (bkt == 0 && t == 0) noffs[N] = E;
  __syncthreads();
  // scatter within the bucket's ~16KB window (L2-resident, no write amp)
  for (int i = s + t; i < e; i += TPB) {
    int2 p = ebuf[i];
    int pos = atomicAdd(&cursor[p.x & 63], 1);
    csr[pos] = make_int2(p.x >> 6, p.y);
  }
}

// ---------------- Layer-1 aggregation: 16 threads/node, f<9 active ----------------
__global__ void __launch_bounds__(256) k_agg1(
    const float* __restrict__ x, const int2* __restrict__ csr,
    const int* __restrict__ noffs, const float* __restrict__ We1,
    const float* __restrict__ be1, float* __restrict__ u1, int N) {
  int t = blockIdx.x * TPB + threadIdx.x;
  int node = t >> 4, f = t & 15;
  if (node >= N || f >= 9) return;
  int o0 = noffs[node], o1 = noffs[node + 1];
  float we = We1[f], be = be1[f];
  float acc = 0.f;
  int e = o0;
  for (; e + 3 < o1; e += 4) {
    int2 p0 = csr[e], p1 = csr[e + 1], p2 = csr[e + 2], p3 = csr[e + 3];
    float v0 = x[p0.x * 9 + f] + fmaf(__int_as_float(p0.y), we, be);
    float v1 = x[p1.x * 9 + f] + fmaf(__int_as_float(p1.y), we, be);
    float v2 = x[p2.x * 9 + f] + fmaf(__int_as_float(p2.y), we, be);
    float v3 = x[p3.x * 9 + f] + fmaf(__int_as_float(p3.y), we, be);
    acc += fmaxf(v0, 0.f) + fmaxf(v1, 0.f) + fmaxf(v2, 0.f) + fmaxf(v3, 0.f);
  }
  for (; e < o1; ++e) {
    int2 p = csr[e];
    acc += fmaxf(x[p.x * 9 + f] + fmaf(__int_as_float(p.y), we, be), 0.f);
  }
  u1[node * 9 + f] = x[node * 9 + f] + acc;
}

// ---------------- Layer-2 aggregation: one wave per node, 8 gathers in flight ----------------
__global__ void __launch_bounds__(256) k_agg2(
    const float* __restrict__ h1, const int2* __restrict__ csr,
    const int* __restrict__ noffs, const float* __restrict__ We2,
    const float* __restrict__ be2, float* __restrict__ u2, int N) {
  int gt = blockIdx.x * TPB + threadIdx.x;
  int node = gt >> 6, f = gt & 63;
  if (node >= N) return;
  int o0 = noffs[node], o1 = noffs[node + 1];
  float we = We2[f], be = be2[f];
  float acc = 0.f;
  int e = o0;
  for (; e + 8 <= o1; e += 8) {
    int2 p[8];
#pragma unroll
    for (int j = 0; j < 8; ++j) p[j] = csr[e + j];
    float v[8];
#pragma unroll
    for (int j = 0; j < 8; ++j) v[j] = h1[p[j].x * 64 + f];
#pragma unroll
    for (int j = 0; j < 8; ++j)
      acc += fmaxf(v[j] + fmaf(__int_as_float(p[j].y), we, be), 0.f);
  }
  for (; e < o1; ++e) {
    int2 p = csr[e];
    acc += fmaxf(h1[p.x * 64 + f] + fmaf(__int_as_float(p.y), we, be), 0.f);
  }
  u2[node * 64 + f] = h1[node * 64 + f] + acc;
}

// ---------------- 2-layer MLP ----------------
template <int KIN>
__global__ void __launch_bounds__(256) k_mlp(
    const float* __restrict__ uin, const float* __restrict__ Wa,
    const float* __restrict__ ba, const float* __restrict__ Wb,
    const float* __restrict__ bb, float* __restrict__ hout, int N) {
  constexpr int US = (KIN == 64) ? 65 : KIN;
  __shared__ float ls_in[64 * US];
  __shared__ float ls_z[64 * 65];
  __shared__ float ls_w[64 * 64];
  __shared__ float ls_b[128];
  const int t = threadIdx.x;
  const int n0 = blockIdx.x * 64;

  for (int i = t; i < 64 * KIN; i += TPB) {
    int r = i / KIN, c = i % KIN;
    int g = n0 + r;
    ls_in[r * US + c] = (g < N) ? uin[g * KIN + c] : 0.f;
  }
  for (int i = t; i < KIN * 64; i += TPB) ls_w[i] = Wa[i];
  if (t < 64) { ls_b[t] = ba[t]; ls_b[64 + t] = bb[t]; }
  __syncthreads();

  const int of = (t & 15) * 4, nb = (t >> 4) * 4;
  float acc[4][4];
#pragma unroll
  for (int i = 0; i < 4; ++i)
#pragma unroll
    for (int j = 0; j < 4; ++j) acc[i][j] = 0.f;

  for (int k = 0; k < KIN; ++k) {
    float4 w = *(const float4*)&ls_w[k * 64 + of];
#pragma unroll
    for (int ni = 0; ni < 4; ++ni) {
      float uv = ls_in[(nb + ni) * US + k];
      acc[ni][0] += uv * w.x; acc[ni][1] += uv * w.y;
      acc[ni][2] += uv * w.z; acc[ni][3] += uv * w.w;
    }
  }
#pragma unroll
  for (int ni = 0; ni < 4; ++ni)
#pragma unroll
    for (int oi = 0; oi < 4; ++oi)
      ls_z[(nb + ni) * 65 + of + oi] = fmaxf(acc[ni][oi] + ls_b[of + oi], 0.f);
  __syncthreads();
  for (int i = t; i < 4096; i += TPB) ls_w[i] = Wb[i];
  __syncthreads();

#pragma unroll
  for (int i = 0; i < 4; ++i)
#pragma unroll
    for (int j = 0; j < 4; ++j) acc[i][j] = 0.f;
  for (int k = 0; k < 64; ++k) {
    float4 w = *(const float4*)&ls_w[k * 64 + of];
#pragma unroll
    for (int ni = 0; ni < 4; ++ni) {
      float zv = ls_z[(nb + ni) * 65 + k];
      acc[ni][0] += zv * w.x; acc[ni][1] += zv * w.y;
      acc[ni][2] += zv * w.z; acc[ni][3] += zv * w.w;
    }
  }
#pragma unroll
  for (int ni = 0; ni < 4; ++ni) {
    int n = n0 + nb + ni;
    if (n < N) {
      float4 o;
      o.x = fmaxf(acc[ni][0] + ls_b[64 + of + 0], 0.f);
      o.y = fmaxf(acc[ni][1] + ls_b[64 + of + 1], 0.f);
      o.z = fmaxf(acc[ni][2] + ls_b[64 + of + 2], 0.f);
      o.w = fmaxf(acc[ni][3] + ls_b[64 + of + 3], 0.f);
      *(float4*)&hout[n * 64 + of] = o;
    }
  }
}

// ---------------- Readout ----------------
__global__ void __launch_bounds__(256) k_readout(
    const float* __restrict__ h2, const float* __restrict__ Wr1,
    const float* __restrict__ br1, const float* __restrict__ Wr2,
    const float* __restrict__ br2, const int* __restrict__ tmask,
    float* __restrict__ pi, int N) {
  __shared__ float ls_h[32 * 65];
  __shared__ float ls_w[64 * 32];
  __shared__ float ls_w2[32];
  __shared__ float ls_b1[32];
  int t = threadIdx.x;
  int n0 = blockIdx.x * 32;
  for (int i = t; i < 32 * 64; i += TPB) {
    int r = i >> 6, c = i & 63;
    int g = n0 + r;
    ls_h[r * 65 + c] = (g < N) ? h2[g * 64 + c] : 0.f;
  }
  for (int i = t; i < 2048; i += TPB) ls_w[i] = Wr1[i];
  if (t < 32) { ls_w2[t] = Wr2[t]; ls_b1[t] = br1[t]; }
  __syncthreads();
  int of = t & 31, q = t >> 5;
  float b2 = br2[0];
#pragma unroll
  for (int j = 0; j < 4; ++j) {
    int n = q * 4 + j;
    float a = 0.f;
    for (int k = 0; k < 64; ++k) a += ls_h[n * 65 + k] * ls_w[k * 32 + of];
    float r = fmaxf(a + ls_b1[of], 0.f) * ls_w2[of];
    for (int s = 16; s > 0; s >>= 1) r += __shfl_down(r, s, 32);
    if (of == 0) {
      int g = n0 + n;
      if (g < N) {
        float sg = 1.f / (1.f + expf(-(r + b2)));
        pi[g] = sg * (1.f - (float)tmask[g]);
      }
    }
  }
}

// ---------------- Group sums (batch sorted) ----------------
__global__ void k_grpsum(const float* __restrict__ pi, const float* __restrict__ c_cost,
                         const int* __restrict__ batch, float* __restrict__ exp_tot, int N) {
  __shared__ float lsf[256];
  __shared__ int lsi[256];
  int t = threadIdx.x;
  int i = blockIdx.x * TPB + t;
  bool valid = i < N;
  int g = valid ? batch[i] : 0;
  float v = valid ? pi[i] * c_cost[i] : 0.f;
  lsi[t] = valid ? g : 0x7fffffff;
  __syncthreads();
  for (int s = 128; s > 0; s >>= 1) { if (t < s) lsi[t] = min(lsi[t], lsi[t + s]); __syncthreads(); }
  int gmin = lsi[0];
  __syncthreads();
  lsi[t] = valid ? g : -1;
  __syncthreads();
  for (int s = 128; s > 0; s >>= 1) { if (t < s) lsi[t] = max(lsi[t], lsi[t + s]); __syncthreads(); }
  int gmax = lsi[0];
  __syncthreads();
  for (int gg = gmin; gg <= gmax; ++gg) {
    lsf[t] = (valid && g == gg) ? v : 0.f;
    __syncthreads();
    for (int s = 128; s > 0; s >>= 1) { if (t < s) lsf[t] += lsf[t + s]; __syncthreads(); }
    if (t == 0) atomicAdd(&exp_tot[gg], lsf[0]);
    __syncthreads();
  }
}

__global__ void k_final(const float* __restrict__ pi, const int* __restrict__ batch,
                        const float* __restrict__ B_total, const float* __restrict__ exp_tot,
                        float* __restrict__ out, int N) {
  int i = blockIdx.x * TPB + threadIdx.x;
  if (i < N) {
    int g = batch[i];
    float ratio = fminf(B_total[g] / (exp_tot[g] + 1e-12f), 1.f);
    out[i] = pi[i] * ratio;
  }
}

extern "C" void kernel_launch(void* const* d_in, const int* in_sizes, int n_in,
                              void* d_out, int out_size, void* d_ws, size_t ws_size,
                              hipStream_t stream) {
  const float* x     = (const float*)d_in[0];
  const int*   ei    = (const int*)d_in[1];
  const float* eattr = (const float*)d_in[2];
  const int*   batch = (const int*)d_in[3];
  const float* Btot  = (const float*)d_in[4];
  const int*   tmask = (const int*)d_in[5];
  const float* ccost = (const float*)d_in[6];
  const float* We1 = (const float*)d_in[7],  *be1 = (const float*)d_in[8];
  const float* W1a = (const float*)d_in[9],  *b1a = (const float*)d_in[10];
  const float* W1b = (const float*)d_in[11], *b1b = (const float*)d_in[12];
  const float* We2 = (const float*)d_in[13], *be2 = (const float*)d_in[14];
  const float* W2a = (const float*)d_in[15], *b2a = (const float*)d_in[16];
  const float* W2b = (const float*)d_in[17], *b2b = (const float*)d_in[18];
  const float* Wr1 = (const float*)d_in[19], *br1 = (const float*)d_in[20];
  const float* Wr2 = (const float*)d_in[21], *br2 = (const float*)d_in[22];
  float* out = (float*)d_out;

  const int N = in_sizes[0] / 9;
  const int E = in_sizes[2];
  const int G = in_sizes[4];
  const int* src = ei;
  const int* dst = ei + E;
  const int B = (N + 63) >> 6;            // buckets of 64 nodes
  const int nscan = B * P_BLOCKS;         // flat (bin,block) count array

  // workspace carve-up (4-byte elements)
  size_t cur = 0;
  auto alloc = [&](size_t elems) { size_t r = cur; cur += elems; cur = (cur + 63) & ~(size_t)63; return r; };
  char* wsb = (char*)d_ws;
  size_t o_exp    = alloc(G);             // zeroed
  size_t o_counts = alloc(nscan);
  size_t o_offs   = alloc(nscan + 1);
  size_t o_bsums  = alloc(256);
  size_t o_noffs  = alloc(N + 1);
  size_t o_csr    = alloc(2 * (size_t)E);
  size_t e_or_h   = (2 * (size_t)E > (size_t)N * 64) ? 2 * (size_t)E : (size_t)N * 64;
  size_t o_ebuf   = alloc(e_or_h);        // ebuf (dead after k_bsort) aliased with h1
  size_t o_u1     = alloc((size_t)N * 9);
  size_t o_u2     = alloc((size_t)N * 64);
  size_t o_pi     = alloc(N);
  (void)ws_size;

  float* exp_t  = (float*)wsb + o_exp;
  int*   counts = (int*)wsb + o_counts;
  int*   offs   = (int*)wsb + o_offs;
  int*   bsums  = (int*)wsb + o_bsums;
  int*   noffs  = (int*)wsb + o_noffs;
  int2*  csr    = (int2*)((int*)wsb + o_csr);
  int2*  ebuf   = (int2*)((int*)wsb + o_ebuf);
  float* h1     = (float*)wsb + o_ebuf;   // alias: ebuf dead before h1 written
  float* u1     = (float*)wsb + o_u1;
  float* u2     = (float*)wsb + o_u2;
  float* pi     = (float*)wsb + o_pi;

  hipMemsetAsync(exp_t, 0, (size_t)G * 4, stream);

  const int nb = (nscan + 1023) / 1024;

  k_bhist<<<P_BLOCKS, TPB, 0, stream>>>(dst, counts, E, B);
  k_scan_block<<<nb, TPB, 0, stream>>>(counts, offs, bsums, nscan);
  k_scan_mid<<<1, 256, 0, stream>>>(bsums, nb);
  k_scan_add<<<nb, TPB, 0, stream>>>(offs, bsums, nscan, E);
  k_bfill<<<P_BLOCKS, TPB, 0, stream>>>(src, dst, eattr, offs, ebuf, E, B);
  k_bsort<<<B, TPB, 0, stream>>>(ebuf, offs, csr, noffs, N, E);

  k_agg1<<<((size_t)N * 16 + TPB - 1) / TPB, TPB, 0, stream>>>(x, csr, noffs, We1, be1, u1, N);
  k_mlp<9><<<(N + 63) / 64, TPB, 0, stream>>>(u1, W1a, b1a, W1b, b1b, h1, N);

  k_agg2<<<((size_t)N * 64 + TPB - 1) / TPB, TPB, 0, stream>>>(h1, csr, noffs, We2, be2, u2, N);
  k_mlp<64><<<(N + 63) / 64, TPB, 0, stream>>>(u2, W2a, b2a, W2b, b2b, u2, N);

  k_readout<<<(N + 31) / 32, TPB, 0, stream>>>(u2, Wr1, br1, Wr2, br2, tmask, pi, N);
  k_grpsum<<<(N + TPB - 1) / TPB, TPB, 0, stream>>>(pi, ccost, batch, exp_t, N);
  k_final<<<(N + TPB - 1) / TPB, TPB, 0, stream>>>(pi, batch, Btot, exp_t, out, N);
}

// Round 5
// 520.227 us; speedup vs baseline: 3.3308x; 1.0773x over previous
//
#include <hip/hip_runtime.h>
#include <math.h>

#define TPB 256
#define P_BLOCKS 512
#define BSHIFT 8          // 256 nodes per bin
#define BINS_MAX 512      // >= ceil(100000/256)=391

// ---------------- bucketed histogram: counts[bin*P + blk] ----------------
__global__ void __launch_bounds__(256) k_bhist(const int* __restrict__ dst,
                                               int* __restrict__ counts, int E, int B) {
  __shared__ int h[BINS_MAX];
  int t = threadIdx.x, blk = blockIdx.x;
  for (int i = t; i < B; i += TPB) h[i] = 0;
  __syncthreads();
  int chunk = (E + P_BLOCKS - 1) / P_BLOCKS;
  int s = blk * chunk, e = min(E, s + chunk);
  for (int i = s + t; i < e; i += TPB)
    atomicAdd(&h[__builtin_nontemporal_load(&dst[i]) >> BSHIFT], 1);
  __syncthreads();
  for (int i = t; i < B; i += TPB) counts[i * P_BLOCKS + blk] = h[i];
}

// ---------------- scan (1024 items/block) ----------------
__global__ void k_scan_block(const int* __restrict__ deg, int* __restrict__ offs,
                             int* __restrict__ bsums, int n) {
  __shared__ int lds[256];
  int t = threadIdx.x, b = blockIdx.x;
  int base = b * 1024 + t * 4;
  int v0 = (base + 0 < n) ? deg[base + 0] : 0;
  int v1 = (base + 1 < n) ? deg[base + 1] : 0;
  int v2 = (base + 2 < n) ? deg[base + 2] : 0;
  int v3 = (base + 3 < n) ? deg[base + 3] : 0;
  int s = v0 + v1 + v2 + v3;
  lds[t] = s;
  __syncthreads();
  int acc = s;
  for (int off = 1; off < 256; off <<= 1) {
    int x = (t >= off) ? lds[t - off] : 0;
    __syncthreads();
    acc += x;
    lds[t] = acc;
    __syncthreads();
  }
  int excl = acc - s;
  if (base + 0 < n) offs[base + 0] = excl;
  if (base + 1 < n) offs[base + 1] = excl + v0;
  if (base + 2 < n) offs[base + 2] = excl + v0 + v1;
  if (base + 3 < n) offs[base + 3] = excl + v0 + v1 + v2;
  if (t == 255) bsums[b] = acc;
}

__global__ void k_scan_mid(int* __restrict__ bsums, int nb) {
  __shared__ int lds[256];
  int t = threadIdx.x;
  int v = (t < nb) ? bsums[t] : 0;
  lds[t] = v;
  __syncthreads();
  int acc = v;
  for (int off = 1; off < 256; off <<= 1) {
    int x = (t >= off) ? lds[t - off] : 0;
    __syncthreads();
    acc += x;
    lds[t] = acc;
    __syncthreads();
  }
  if (t < nb) bsums[t] = acc - v;  // exclusive
}

__global__ void k_scan_add(int* __restrict__ offs, const int* __restrict__ bsums,
                           int n, int total) {
  int t = threadIdx.x, b = blockIdx.x;
  int add = bsums[b];
  int base = b * 1024 + t * 4;
#pragma unroll
  for (int j = 0; j < 4; ++j)
    if (base + j < n) offs[base + j] += add;
  if (b == 0 && t == 0) offs[n] = total;
}

// ---------------- fill: atomic-free (LDS cursors), streaming bin appends ----------------
__global__ void __launch_bounds__(256) k_bfill(const int* __restrict__ src,
                                               const int* __restrict__ dst,
                                               const float* __restrict__ attr,
                                               const int* __restrict__ offs,
                                               int2* __restrict__ ebuf, int E, int B) {
  __shared__ int cur[BINS_MAX];
  int t = threadIdx.x, blk = blockIdx.x;
  for (int i = t; i < B; i += TPB) cur[i] = offs[i * P_BLOCKS + blk];
  __syncthreads();
  int chunk = (E + P_BLOCKS - 1) / P_BLOCKS;
  int s = blk * chunk, e = min(E, s + chunk);
#pragma unroll 4
  for (int i = s + t; i < e; i += TPB) {
    int d = __builtin_nontemporal_load(&dst[i]);
    int sv = __builtin_nontemporal_load(&src[i]);
    float av = __builtin_nontemporal_load(&attr[i]);
    int bin = d >> BSHIFT;
    int pos = atomicAdd(&cur[bin], 1);
    ebuf[pos] = make_int2((sv << BSHIFT) | (d & ((1 << BSHIFT) - 1)), __float_as_int(av));
  }
}

// ---------------- per-bin counting sort -> dst-sorted csr + node offsets ----------------
__global__ void __launch_bounds__(256) k_bsort(const long long* __restrict__ ebuf,
                                               const int* __restrict__ offs,
                                               int2* __restrict__ csr,
                                               int* __restrict__ noffs,
                                               int N, int E) {
  __shared__ int hist[256];
  __shared__ int cursor[256];
  __shared__ int sc[256];
  int t = threadIdx.x, bkt = blockIdx.x;
  hist[t] = 0;
  __syncthreads();
  int s = offs[bkt * P_BLOCKS], e = offs[(bkt + 1) * P_BLOCKS];
#pragma unroll 4
  for (int i = s + t; i < e; i += TPB) {
    long long pv = __builtin_nontemporal_load(&ebuf[i]);
    int key = (int)(unsigned int)(pv & 0xffffffffLL);
    atomicAdd(&hist[key & 255], 1);
  }
  __syncthreads();
  int v = hist[t];
  int acc = v;
  sc[t] = v;
  __syncthreads();
  for (int off = 1; off < 256; off <<= 1) {
    int x = (t >= off) ? sc[t - off] : 0;
    __syncthreads();
    acc += x;
    sc[t] = acc;
    __syncthreads();
  }
  int base = s + acc - v;  // exclusive within bucket
  cursor[t] = base;
  int n = (bkt << BSHIFT) + t;
  if (n < N) noffs[n] = base;
  if (bkt == 0 && t == 0) noffs[N] = E;
  __syncthreads();
  // scatter within the bucket's ~64KB window (L2-resident, no write amp)
#pragma unroll 4
  for (int i = s + t; i < e; i += TPB) {
    long long pv = __builtin_nontemporal_load(&ebuf[i]);
    int key = (int)(unsigned int)(pv & 0xffffffffLL);
    int attr = (int)(unsigned int)(((unsigned long long)pv) >> 32);
    int pos = atomicAdd(&cursor[key & 255], 1);
    csr[pos] = make_int2(((unsigned int)key) >> BSHIFT, attr);
  }
}

// ---------------- Layer-1 aggregation: 16 threads/node, f<9 active ----------------
__global__ void __launch_bounds__(256) k_agg1(
    const float* __restrict__ x, const int2* __restrict__ csr,
    const int* __restrict__ noffs, const float* __restrict__ We1,
    const float* __restrict__ be1, float* __restrict__ u1, int N) {
  int t = blockIdx.x * TPB + threadIdx.x;
  int node = t >> 4, f = t & 15;
  if (node >= N || f >= 9) return;
  int o0 = noffs[node], o1 = noffs[node + 1];
  float we = We1[f], be = be1[f];
  float acc = 0.f;
  int e = o0;
  for (; e + 3 < o1; e += 4) {
    int2 p0 = csr[e], p1 = csr[e + 1], p2 = csr[e + 2], p3 = csr[e + 3];
    float v0 = x[p0.x * 9 + f] + fmaf(__int_as_float(p0.y), we, be);
    float v1 = x[p1.x * 9 + f] + fmaf(__int_as_float(p1.y), we, be);
    float v2 = x[p2.x * 9 + f] + fmaf(__int_as_float(p2.y), we, be);
    float v3 = x[p3.x * 9 + f] + fmaf(__int_as_float(p3.y), we, be);
    acc += fmaxf(v0, 0.f) + fmaxf(v1, 0.f) + fmaxf(v2, 0.f) + fmaxf(v3, 0.f);
  }
  for (; e < o1; ++e) {
    int2 p = csr[e];
    acc += fmaxf(x[p.x * 9 + f] + fmaf(__int_as_float(p.y), we, be), 0.f);
  }
  u1[node * 9 + f] = x[node * 9 + f] + acc;
}

// ---------------- Layer-2 aggregation: one wave per node, 8 gathers in flight ----------------
__global__ void __launch_bounds__(256) k_agg2(
    const float* __restrict__ h1, const int2* __restrict__ csr,
    const int* __restrict__ noffs, const float* __restrict__ We2,
    const float* __restrict__ be2, float* __restrict__ u2, int N) {
  int gt = blockIdx.x * TPB + threadIdx.x;
  int node = gt >> 6, f = gt & 63;
  if (node >= N) return;
  int o0 = noffs[node], o1 = noffs[node + 1];
  float we = We2[f], be = be2[f];
  float acc = 0.f;
  int e = o0;
  for (; e + 8 <= o1; e += 8) {
    int2 p[8];
#pragma unroll
    for (int j = 0; j < 8; ++j) p[j] = csr[e + j];
    float v[8];
#pragma unroll
    for (int j = 0; j < 8; ++j) v[j] = h1[p[j].x * 64 + f];
#pragma unroll
    for (int j = 0; j < 8; ++j)
      acc += fmaxf(v[j] + fmaf(__int_as_float(p[j].y), we, be), 0.f);
  }
  for (; e < o1; ++e) {
    int2 p = csr[e];
    acc += fmaxf(h1[p.x * 64 + f] + fmaf(__int_as_float(p.y), we, be), 0.f);
  }
  u2[node * 64 + f] = h1[node * 64 + f] + acc;
}

// ---------------- 2-layer MLP ----------------
template <int KIN>
__global__ void __launch_bounds__(256) k_mlp(
    const float* __restrict__ uin, const float* __restrict__ Wa,
    const float* __restrict__ ba, const float* __restrict__ Wb,
    const float* __restrict__ bb, float* __restrict__ hout, int N) {
  constexpr int US = (KIN == 64) ? 65 : KIN;
  __shared__ float ls_in[64 * US];
  __shared__ float ls_z[64 * 65];
  __shared__ float ls_w[64 * 64];
  __shared__ float ls_b[128];
  const int t = threadIdx.x;
  const int n0 = blockIdx.x * 64;

  for (int i = t; i < 64 * KIN; i += TPB) {
    int r = i / KIN, c = i % KIN;
    int g = n0 + r;
    ls_in[r * US + c] = (g < N) ? uin[g * KIN + c] : 0.f;
  }
  for (int i = t; i < KIN * 64; i += TPB) ls_w[i] = Wa[i];
  if (t < 64) { ls_b[t] = ba[t]; ls_b[64 + t] = bb[t]; }
  __syncthreads();

  const int of = (t & 15) * 4, nb = (t >> 4) * 4;
  float acc[4][4];
#pragma unroll
  for (int i = 0; i < 4; ++i)
#pragma unroll
    for (int j = 0; j < 4; ++j) acc[i][j] = 0.f;

  for (int k = 0; k < KIN; ++k) {
    float4 w = *(const float4*)&ls_w[k * 64 + of];
#pragma unroll
    for (int ni = 0; ni < 4; ++ni) {
      float uv = ls_in[(nb + ni) * US + k];
      acc[ni][0] += uv * w.x; acc[ni][1] += uv * w.y;
      acc[ni][2] += uv * w.z; acc[ni][3] += uv * w.w;
    }
  }
#pragma unroll
  for (int ni = 0; ni < 4; ++ni)
#pragma unroll
    for (int oi = 0; oi < 4; ++oi)
      ls_z[(nb + ni) * 65 + of + oi] = fmaxf(acc[ni][oi] + ls_b[of + oi], 0.f);
  __syncthreads();
  for (int i = t; i < 4096; i += TPB) ls_w[i] = Wb[i];
  __syncthreads();

#pragma unroll
  for (int i = 0; i < 4; ++i)
#pragma unroll
    for (int j = 0; j < 4; ++j) acc[i][j] = 0.f;
  for (int k = 0; k < 64; ++k) {
    float4 w = *(const float4*)&ls_w[k * 64 + of];
#pragma unroll
    for (int ni = 0; ni < 4; ++ni) {
      float zv = ls_z[(nb + ni) * 65 + k];
      acc[ni][0] += zv * w.x; acc[ni][1] += zv * w.y;
      acc[ni][2] += zv * w.z; acc[ni][3] += zv * w.w;
    }
  }
#pragma unroll
  for (int ni = 0; ni < 4; ++ni) {
    int n = n0 + nb + ni;
    if (n < N) {
      float4 o;
      o.x = fmaxf(acc[ni][0] + ls_b[64 + of + 0], 0.f);
      o.y = fmaxf(acc[ni][1] + ls_b[64 + of + 1], 0.f);
      o.z = fmaxf(acc[ni][2] + ls_b[64 + of + 2], 0.f);
      o.w = fmaxf(acc[ni][3] + ls_b[64 + of + 3], 0.f);
      *(float4*)&hout[n * 64 + of] = o;
    }
  }
}

// ---------------- Readout ----------------
__global__ void __launch_bounds__(256) k_readout(
    const float* __restrict__ h2, const float* __restrict__ Wr1,
    const float* __restrict__ br1, const float* __restrict__ Wr2,
    const float* __restrict__ br2, const int* __restrict__ tmask,
    float* __restrict__ pi, int N) {
  __shared__ float ls_h[32 * 65];
  __shared__ float ls_w[64 * 32];
  __shared__ float ls_w2[32];
  __shared__ float ls_b1[32];
  int t = threadIdx.x;
  int n0 = blockIdx.x * 32;
  for (int i = t; i < 32 * 64; i += TPB) {
    int r = i >> 6, c = i & 63;
    int g = n0 + r;
    ls_h[r * 65 + c] = (g < N) ? h2[g * 64 + c] : 0.f;
  }
  for (int i = t; i < 2048; i += TPB) ls_w[i] = Wr1[i];
  if (t < 32) { ls_w2[t] = Wr2[t]; ls_b1[t] = br1[t]; }
  __syncthreads();
  int of = t & 31, q = t >> 5;
  float b2 = br2[0];
#pragma unroll
  for (int j = 0; j < 4; ++j) {
    int n = q * 4 + j;
    float a = 0.f;
    for (int k = 0; k < 64; ++k) a += ls_h[n * 65 + k] * ls_w[k * 32 + of];
    float r = fmaxf(a + ls_b1[of], 0.f) * ls_w2[of];
    for (int s = 16; s > 0; s >>= 1) r += __shfl_down(r, s, 32);
    if (of == 0) {
      int g = n0 + n;
      if (g < N) {
        float sg = 1.f / (1.f + expf(-(r + b2)));
        pi[g] = sg * (1.f - (float)tmask[g]);
      }
    }
  }
}

// ---------------- Group sums (batch sorted) ----------------
__global__ void k_grpsum(const float* __restrict__ pi, const float* __restrict__ c_cost,
                         const int* __restrict__ batch, float* __restrict__ exp_tot, int N) {
  __shared__ float lsf[256];
  __shared__ int lsi[256];
  int t = threadIdx.x;
  int i = blockIdx.x * TPB + t;
  bool valid = i < N;
  int g = valid ? batch[i] : 0;
  float v = valid ? pi[i] * c_cost[i] : 0.f;
  lsi[t] = valid ? g : 0x7fffffff;
  __syncthreads();
  for (int s = 128; s > 0; s >>= 1) { if (t < s) lsi[t] = min(lsi[t], lsi[t + s]); __syncthreads(); }
  int gmin = lsi[0];
  __syncthreads();
  lsi[t] = valid ? g : -1;
  __syncthreads();
  for (int s = 128; s > 0; s >>= 1) { if (t < s) lsi[t] = max(lsi[t], lsi[t + s]); __syncthreads(); }
  int gmax = lsi[0];
  __syncthreads();
  for (int gg = gmin; gg <= gmax; ++gg) {
    lsf[t] = (valid && g == gg) ? v : 0.f;
    __syncthreads();
    for (int s = 128; s > 0; s >>= 1) { if (t < s) lsf[t] += lsf[t + s]; __syncthreads(); }
    if (t == 0) atomicAdd(&exp_tot[gg], lsf[0]);
    __syncthreads();
  }
}

__global__ void k_final(const float* __restrict__ pi, const int* __restrict__ batch,
                        const float* __restrict__ B_total, const float* __restrict__ exp_tot,
                        float* __restrict__ out, int N) {
  int i = blockIdx.x * TPB + threadIdx.x;
  if (i < N) {
    int g = batch[i];
    float ratio = fminf(B_total[g] / (exp_tot[g] + 1e-12f), 1.f);
    out[i] = pi[i] * ratio;
  }
}

extern "C" void kernel_launch(void* const* d_in, const int* in_sizes, int n_in,
                              void* d_out, int out_size, void* d_ws, size_t ws_size,
                              hipStream_t stream) {
  const float* x     = (const float*)d_in[0];
  const int*   ei    = (const int*)d_in[1];
  const float* eattr = (const float*)d_in[2];
  const int*   batch = (const int*)d_in[3];
  const float* Btot  = (const float*)d_in[4];
  const int*   tmask = (const int*)d_in[5];
  const float* ccost = (const float*)d_in[6];
  const float* We1 = (const float*)d_in[7],  *be1 = (const float*)d_in[8];
  const float* W1a = (const float*)d_in[9],  *b1a = (const float*)d_in[10];
  const float* W1b = (const float*)d_in[11], *b1b = (const float*)d_in[12];
  const float* We2 = (const float*)d_in[13], *be2 = (const float*)d_in[14];
  const float* W2a = (const float*)d_in[15], *b2a = (const float*)d_in[16];
  const float* W2b = (const float*)d_in[17], *b2b = (const float*)d_in[18];
  const float* Wr1 = (const float*)d_in[19], *br1 = (const float*)d_in[20];
  const float* Wr2 = (const float*)d_in[21], *br2 = (const float*)d_in[22];
  float* out = (float*)d_out;

  const int N = in_sizes[0] / 9;
  const int E = in_sizes[2];
  const int G = in_sizes[4];
  const int* src = ei;
  const int* dst = ei + E;
  const int B = (N + (1 << BSHIFT) - 1) >> BSHIFT;  // 256-node bins
  const int nscan = B * P_BLOCKS;

  // workspace carve-up (4-byte elements)
  size_t cur = 0;
  auto alloc = [&](size_t elems) { size_t r = cur; cur += elems; cur = (cur + 63) & ~(size_t)63; return r; };
  char* wsb = (char*)d_ws;
  size_t o_exp    = alloc(G);             // zeroed
  size_t o_counts = alloc(nscan);
  size_t o_offs   = alloc(nscan + 1);
  size_t o_bsums  = alloc(256);
  size_t o_noffs  = alloc(N + 1);
  size_t o_csr    = alloc(2 * (size_t)E);
  size_t e_or_h   = (2 * (size_t)E > (size_t)N * 64) ? 2 * (size_t)E : (size_t)N * 64;
  size_t o_ebuf   = alloc(e_or_h);        // ebuf (dead after k_bsort) aliased with h1
  size_t o_u1     = alloc((size_t)N * 9);
  size_t o_u2     = alloc((size_t)N * 64);
  size_t o_pi     = alloc(N);
  (void)ws_size;

  float* exp_t  = (float*)wsb + o_exp;
  int*   counts = (int*)wsb + o_counts;
  int*   offs   = (int*)wsb + o_offs;
  int*   bsums  = (int*)wsb + o_bsums;
  int*   noffs  = (int*)wsb + o_noffs;
  int2*  csr    = (int2*)((int*)wsb + o_csr);
  int2*  ebuf   = (int2*)((int*)wsb + o_ebuf);
  float* h1     = (float*)wsb + o_ebuf;   // alias: ebuf dead before h1 written
  float* u1     = (float*)wsb + o_u1;
  float* u2     = (float*)wsb + o_u2;
  float* pi     = (float*)wsb + o_pi;

  (void)hipMemsetAsync(exp_t, 0, (size_t)G * 4, stream);

  const int nb = (nscan + 1023) / 1024;

  k_bhist<<<P_BLOCKS, TPB, 0, stream>>>(dst, counts, E, B);
  k_scan_block<<<nb, TPB, 0, stream>>>(counts, offs, bsums, nscan);
  k_scan_mid<<<1, 256, 0, stream>>>(bsums, nb);
  k_scan_add<<<nb, TPB, 0, stream>>>(offs, bsums, nscan, E);
  k_bfill<<<P_BLOCKS, TPB, 0, stream>>>(src, dst, eattr, offs, ebuf, E, B);
  k_bsort<<<B, TPB, 0, stream>>>((const long long*)ebuf, offs, csr, noffs, N, E);

  k_agg1<<<((size_t)N * 16 + TPB - 1) / TPB, TPB, 0, stream>>>(x, csr, noffs, We1, be1, u1, N);
  k_mlp<9><<<(N + 63) / 64, TPB, 0, stream>>>(u1, W1a, b1a, W1b, b1b, h1, N);

  k_agg2<<<((size_t)N * 64 + TPB - 1) / TPB, TPB, 0, stream>>>(h1, csr, noffs, We2, be2, u2, N);
  k_mlp<64><<<(N + 63) / 64, TPB, 0, stream>>>(u2, W2a, b2a, W2b, b2b, u2, N);

  k_readout<<<(N + 31) / 32, TPB, 0, stream>>>(u2, Wr1, br1, Wr2, br2, tmask, pi, N);
  k_grpsum<<<(N + TPB - 1) / TPB, TPB, 0, stream>>>(pi, ccost, batch, exp_t, N);
  k_final<<<(N + TPB - 1) / TPB, TPB, 0, stream>>>(pi, batch, Btot, exp_t, out, N);
}

// Round 6
// 488.163 us; speedup vs baseline: 3.5496x; 1.0657x over previous
//
#include <hip/hip_runtime.h>
#include <hip/hip_fp16.h>
#include <math.h>

#define TPB 256
#define P_BLOCKS 512
#define BSHIFT 8          // 256 nodes per bin
#define BINS_MAX 512      // >= ceil(100000/256)=391

struct alignas(8) h2x2 { __half2 a, b; };

// ---------------- bucketed histogram: counts[bin*P + blk] ----------------
__global__ void __launch_bounds__(256) k_bhist(const int* __restrict__ dst,
                                               int* __restrict__ counts, int E, int B) {
  __shared__ int h[BINS_MAX];
  int t = threadIdx.x, blk = blockIdx.x;
  for (int i = t; i < B; i += TPB) h[i] = 0;
  __syncthreads();
  int chunk = (E + P_BLOCKS - 1) / P_BLOCKS;
  int s = blk * chunk, e = min(E, s + chunk);
  for (int i = s + t; i < e; i += TPB)
    atomicAdd(&h[__builtin_nontemporal_load(&dst[i]) >> BSHIFT], 1);
  __syncthreads();
  for (int i = t; i < B; i += TPB) counts[i * P_BLOCKS + blk] = h[i];
}

// ---------------- scan (1024 items/block) ----------------
__global__ void k_scan_block(const int* __restrict__ deg, int* __restrict__ offs,
                             int* __restrict__ bsums, int n) {
  __shared__ int lds[256];
  int t = threadIdx.x, b = blockIdx.x;
  int base = b * 1024 + t * 4;
  int v0 = (base + 0 < n) ? deg[base + 0] : 0;
  int v1 = (base + 1 < n) ? deg[base + 1] : 0;
  int v2 = (base + 2 < n) ? deg[base + 2] : 0;
  int v3 = (base + 3 < n) ? deg[base + 3] : 0;
  int s = v0 + v1 + v2 + v3;
  lds[t] = s;
  __syncthreads();
  int acc = s;
  for (int off = 1; off < 256; off <<= 1) {
    int x = (t >= off) ? lds[t - off] : 0;
    __syncthreads();
    acc += x;
    lds[t] = acc;
    __syncthreads();
  }
  int excl = acc - s;
  if (base + 0 < n) offs[base + 0] = excl;
  if (base + 1 < n) offs[base + 1] = excl + v0;
  if (base + 2 < n) offs[base + 2] = excl + v0 + v1;
  if (base + 3 < n) offs[base + 3] = excl + v0 + v1 + v2;
  if (t == 255) bsums[b] = acc;
}

__global__ void k_scan_mid(int* __restrict__ bsums, int nb) {
  __shared__ int lds[256];
  int t = threadIdx.x;
  int v = (t < nb) ? bsums[t] : 0;
  lds[t] = v;
  __syncthreads();
  int acc = v;
  for (int off = 1; off < 256; off <<= 1) {
    int x = (t >= off) ? lds[t - off] : 0;
    __syncthreads();
    acc += x;
    lds[t] = acc;
    __syncthreads();
  }
  if (t < nb) bsums[t] = acc - v;  // exclusive
}

__global__ void k_scan_add(int* __restrict__ offs, const int* __restrict__ bsums,
                           int n, int total) {
  int t = threadIdx.x, b = blockIdx.x;
  int add = bsums[b];
  int base = b * 1024 + t * 4;
#pragma unroll
  for (int j = 0; j < 4; ++j)
    if (base + j < n) offs[base + j] += add;
  if (b == 0 && t == 0) offs[n] = total;
}

// ---------------- fill: atomic-free (LDS cursors), streaming bin appends ----------------
__global__ void __launch_bounds__(256) k_bfill(const int* __restrict__ src,
                                               const int* __restrict__ dst,
                                               const float* __restrict__ attr,
                                               const int* __restrict__ offs,
                                               int2* __restrict__ ebuf, int E, int B) {
  __shared__ int cur[BINS_MAX];
  int t = threadIdx.x, blk = blockIdx.x;
  for (int i = t; i < B; i += TPB) cur[i] = offs[i * P_BLOCKS + blk];
  __syncthreads();
  int chunk = (E + P_BLOCKS - 1) / P_BLOCKS;
  int s = blk * chunk, e = min(E, s + chunk);
#pragma unroll 4
  for (int i = s + t; i < e; i += TPB) {
    int d = __builtin_nontemporal_load(&dst[i]);
    int sv = __builtin_nontemporal_load(&src[i]);
    float av = __builtin_nontemporal_load(&attr[i]);
    int bin = d >> BSHIFT;
    int pos = atomicAdd(&cur[bin], 1);
    ebuf[pos] = make_int2((sv << BSHIFT) | (d & ((1 << BSHIFT) - 1)), __float_as_int(av));
  }
}

// ---------------- per-bin counting sort -> dst-sorted csr + node offsets ----------------
__global__ void __launch_bounds__(256) k_bsort(const long long* __restrict__ ebuf,
                                               const int* __restrict__ offs,
                                               int2* __restrict__ csr,
                                               int* __restrict__ noffs,
                                               int N, int E) {
  __shared__ int hist[256];
  __shared__ int cursor[256];
  __shared__ int sc[256];
  int t = threadIdx.x, bkt = blockIdx.x;
  hist[t] = 0;
  __syncthreads();
  int s = offs[bkt * P_BLOCKS], e = offs[(bkt + 1) * P_BLOCKS];
#pragma unroll 4
  for (int i = s + t; i < e; i += TPB) {
    long long pv = __builtin_nontemporal_load(&ebuf[i]);
    int key = (int)(unsigned int)(pv & 0xffffffffLL);
    atomicAdd(&hist[key & 255], 1);
  }
  __syncthreads();
  int v = hist[t];
  int acc = v;
  sc[t] = v;
  __syncthreads();
  for (int off = 1; off < 256; off <<= 1) {
    int x = (t >= off) ? sc[t - off] : 0;
    __syncthreads();
    acc += x;
    sc[t] = acc;
    __syncthreads();
  }
  int base = s + acc - v;  // exclusive within bucket
  cursor[t] = base;
  int n = (bkt << BSHIFT) + t;
  if (n < N) noffs[n] = base;
  if (bkt == 0 && t == 0) noffs[N] = E;
  __syncthreads();
#pragma unroll 4
  for (int i = s + t; i < e; i += TPB) {
    long long pv = __builtin_nontemporal_load(&ebuf[i]);
    int key = (int)(unsigned int)(pv & 0xffffffffLL);
    int attr = (int)(unsigned int)(((unsigned long long)pv) >> 32);
    int pos = atomicAdd(&cursor[key & 255], 1);
    csr[pos] = make_int2(((unsigned int)key) >> BSHIFT, attr);
  }
}

// ---------------- Layer-1 aggregation: 16 threads/node, f<9 active ----------------
__global__ void __launch_bounds__(256) k_agg1(
    const float* __restrict__ x, const int2* __restrict__ csr,
    const int* __restrict__ noffs, const float* __restrict__ We1,
    const float* __restrict__ be1, float* __restrict__ u1, int N) {
  int t = blockIdx.x * TPB + threadIdx.x;
  int node = t >> 4, f = t & 15;
  if (node >= N || f >= 9) return;
  int o0 = noffs[node], o1 = noffs[node + 1];
  float we = We1[f], be = be1[f];
  float acc = 0.f;
  int e = o0;
  for (; e + 3 < o1; e += 4) {
    int2 p0 = csr[e], p1 = csr[e + 1], p2 = csr[e + 2], p3 = csr[e + 3];
    float v0 = x[p0.x * 9 + f] + fmaf(__int_as_float(p0.y), we, be);
    float v1 = x[p1.x * 9 + f] + fmaf(__int_as_float(p1.y), we, be);
    float v2 = x[p2.x * 9 + f] + fmaf(__int_as_float(p2.y), we, be);
    float v3 = x[p3.x * 9 + f] + fmaf(__int_as_float(p3.y), we, be);
    acc += fmaxf(v0, 0.f) + fmaxf(v1, 0.f) + fmaxf(v2, 0.f) + fmaxf(v3, 0.f);
  }
  for (; e < o1; ++e) {
    int2 p = csr[e];
    acc += fmaxf(x[p.x * 9 + f] + fmaf(__int_as_float(p.y), we, be), 0.f);
  }
  u1[node * 9 + f] = x[node * 9 + f] + acc;
}

// ---------------- Layer-2 aggregation: one wave/node, fp16 rows, half4 gathers ----------------
// lane = (q,c): quarter q handles edges e+q (mod 4); chunk c covers features c*4..c*4+3.
__global__ void __launch_bounds__(256) k_agg2(
    const __half* __restrict__ h1, const int2* __restrict__ csr,
    const int* __restrict__ noffs, const float* __restrict__ We2,
    const float* __restrict__ be2, float* __restrict__ u2, int N) {
  int gt = blockIdx.x * TPB + threadIdx.x;
  int node = gt >> 6;
  if (node >= N) return;
  int lane = gt & 63;
  int q = lane >> 4, c = lane & 15;
  float4 we = *(const float4*)&We2[c * 4];
  float4 be = *(const float4*)&be2[c * 4];
  int o0 = noffs[node], o1 = noffs[node + 1];
  float a0 = 0.f, a1 = 0.f, a2 = 0.f, a3 = 0.f;
  int e = o0;
  for (; e + 8 <= o1; e += 8) {
    long long pvA = __builtin_nontemporal_load((const long long*)&csr[e + q]);
    long long pvB = __builtin_nontemporal_load((const long long*)&csr[e + 4 + q]);
    int sA = (int)(unsigned int)(pvA & 0xffffffffLL);
    int sB = (int)(unsigned int)(pvB & 0xffffffffLL);
    h2x2 vA = *(const h2x2*)(h1 + (size_t)sA * 64 + c * 4);
    h2x2 vB = *(const h2x2*)(h1 + (size_t)sB * 64 + c * 4);
    float eaA = __int_as_float((int)(unsigned int)(((unsigned long long)pvA) >> 32));
    float eaB = __int_as_float((int)(unsigned int)(((unsigned long long)pvB) >> 32));
    float2 fA0 = __half22float2(vA.a), fA1 = __half22float2(vA.b);
    float2 fB0 = __half22float2(vB.a), fB1 = __half22float2(vB.b);
    a0 += fmaxf(fA0.x + fmaf(eaA, we.x, be.x), 0.f) + fmaxf(fB0.x + fmaf(eaB, we.x, be.x), 0.f);
    a1 += fmaxf(fA0.y + fmaf(eaA, we.y, be.y), 0.f) + fmaxf(fB0.y + fmaf(eaB, we.y, be.y), 0.f);
    a2 += fmaxf(fA1.x + fmaf(eaA, we.z, be.z), 0.f) + fmaxf(fB1.x + fmaf(eaB, we.z, be.z), 0.f);
    a3 += fmaxf(fA1.y + fmaf(eaA, we.w, be.w), 0.f) + fmaxf(fB1.y + fmaf(eaB, we.w, be.w), 0.f);
  }
  for (; e < o1; e += 4) {
    if (e + q < o1) {
      int2 p = csr[e + q];
      h2x2 v = *(const h2x2*)(h1 + (size_t)p.x * 64 + c * 4);
      float ea = __int_as_float(p.y);
      float2 f0 = __half22float2(v.a), f1 = __half22float2(v.b);
      a0 += fmaxf(f0.x + fmaf(ea, we.x, be.x), 0.f);
      a1 += fmaxf(f0.y + fmaf(ea, we.y, be.y), 0.f);
      a2 += fmaxf(f1.x + fmaf(ea, we.z, be.z), 0.f);
      a3 += fmaxf(f1.y + fmaf(ea, we.w, be.w), 0.f);
    }
  }
  a0 += __shfl_xor(a0, 16, 64); a0 += __shfl_xor(a0, 32, 64);
  a1 += __shfl_xor(a1, 16, 64); a1 += __shfl_xor(a1, 32, 64);
  a2 += __shfl_xor(a2, 16, 64); a2 += __shfl_xor(a2, 32, 64);
  a3 += __shfl_xor(a3, 16, 64); a3 += __shfl_xor(a3, 32, 64);
  if (q == 0) {
    h2x2 sf = *(const h2x2*)(h1 + (size_t)node * 64 + c * 4);
    float2 s0 = __half22float2(sf.a), s1 = __half22float2(sf.b);
    float4 o;
    o.x = s0.x + a0; o.y = s0.y + a1; o.z = s1.x + a2; o.w = s1.y + a3;
    *(float4*)&u2[(size_t)node * 64 + c * 4] = o;
  }
}

// ---------------- 2-layer MLP ----------------
template <int KIN, bool HALF_OUT>
__global__ void __launch_bounds__(256) k_mlp(
    const float* __restrict__ uin, const float* __restrict__ Wa,
    const float* __restrict__ ba, const float* __restrict__ Wb,
    const float* __restrict__ bb, void* __restrict__ hout, int N) {
  constexpr int US = (KIN == 64) ? 65 : KIN;
  __shared__ float ls_in[64 * US];
  __shared__ float ls_z[64 * 65];
  __shared__ float ls_w[64 * 64];
  __shared__ float ls_b[128];
  const int t = threadIdx.x;
  const int n0 = blockIdx.x * 64;

  for (int i = t; i < 64 * KIN; i += TPB) {
    int r = i / KIN, c = i % KIN;
    int g = n0 + r;
    ls_in[r * US + c] = (g < N) ? uin[g * KIN + c] : 0.f;
  }
  for (int i = t; i < KIN * 64; i += TPB) ls_w[i] = Wa[i];
  if (t < 64) { ls_b[t] = ba[t]; ls_b[64 + t] = bb[t]; }
  __syncthreads();

  const int of = (t & 15) * 4, nb = (t >> 4) * 4;
  float acc[4][4];
#pragma unroll
  for (int i = 0; i < 4; ++i)
#pragma unroll
    for (int j = 0; j < 4; ++j) acc[i][j] = 0.f;

  for (int k = 0; k < KIN; ++k) {
    float4 w = *(const float4*)&ls_w[k * 64 + of];
#pragma unroll
    for (int ni = 0; ni < 4; ++ni) {
      float uv = ls_in[(nb + ni) * US + k];
      acc[ni][0] += uv * w.x; acc[ni][1] += uv * w.y;
      acc[ni][2] += uv * w.z; acc[ni][3] += uv * w.w;
    }
  }
#pragma unroll
  for (int ni = 0; ni < 4; ++ni)
#pragma unroll
    for (int oi = 0; oi < 4; ++oi)
      ls_z[(nb + ni) * 65 + of + oi] = fmaxf(acc[ni][oi] + ls_b[of + oi], 0.f);
  __syncthreads();
  for (int i = t; i < 4096; i += TPB) ls_w[i] = Wb[i];
  __syncthreads();

#pragma unroll
  for (int i = 0; i < 4; ++i)
#pragma unroll
    for (int j = 0; j < 4; ++j) acc[i][j] = 0.f;
  for (int k = 0; k < 64; ++k) {
    float4 w = *(const float4*)&ls_w[k * 64 + of];
#pragma unroll
    for (int ni = 0; ni < 4; ++ni) {
      float zv = ls_z[(nb + ni) * 65 + k];
      acc[ni][0] += zv * w.x; acc[ni][1] += zv * w.y;
      acc[ni][2] += zv * w.z; acc[ni][3] += zv * w.w;
    }
  }
#pragma unroll
  for (int ni = 0; ni < 4; ++ni) {
    int n = n0 + nb + ni;
    if (n < N) {
      float4 o;
      o.x = fmaxf(acc[ni][0] + ls_b[64 + of + 0], 0.f);
      o.y = fmaxf(acc[ni][1] + ls_b[64 + of + 1], 0.f);
      o.z = fmaxf(acc[ni][2] + ls_b[64 + of + 2], 0.f);
      o.w = fmaxf(acc[ni][3] + ls_b[64 + of + 3], 0.f);
      if (HALF_OUT) {
        h2x2 hv;
        hv.a = __float22half2_rn(make_float2(o.x, o.y));
        hv.b = __float22half2_rn(make_float2(o.z, o.w));
        *(h2x2*)((__half*)hout + (size_t)n * 64 + of) = hv;
      } else {
        *(float4*)((float*)hout + (size_t)n * 64 + of) = o;
      }
    }
  }
}

// ---------------- Readout ----------------
__global__ void __launch_bounds__(256) k_readout(
    const float* __restrict__ h2, const float* __restrict__ Wr1,
    const float* __restrict__ br1, const float* __restrict__ Wr2,
    const float* __restrict__ br2, const int* __restrict__ tmask,
    float* __restrict__ pi, int N) {
  __shared__ float ls_h[32 * 65];
  __shared__ float ls_w[64 * 32];
  __shared__ float ls_w2[32];
  __shared__ float ls_b1[32];
  int t = threadIdx.x;
  int n0 = blockIdx.x * 32;
  for (int i = t; i < 32 * 64; i += TPB) {
    int r = i >> 6, c = i & 63;
    int g = n0 + r;
    ls_h[r * 65 + c] = (g < N) ? h2[g * 64 + c] : 0.f;
  }
  for (int i = t; i < 2048; i += TPB) ls_w[i] = Wr1[i];
  if (t < 32) { ls_w2[t] = Wr2[t]; ls_b1[t] = br1[t]; }
  __syncthreads();
  int of = t & 31, q = t >> 5;
  float b2 = br2[0];
#pragma unroll
  for (int j = 0; j < 4; ++j) {
    int n = q * 4 + j;
    float a = 0.f;
    for (int k = 0; k < 64; ++k) a += ls_h[n * 65 + k] * ls_w[k * 32 + of];
    float r = fmaxf(a + ls_b1[of], 0.f) * ls_w2[of];
    for (int s = 16; s > 0; s >>= 1) r += __shfl_down(r, s, 32);
    if (of == 0) {
      int g = n0 + n;
      if (g < N) {
        float sg = 1.f / (1.f + expf(-(r + b2)));
        pi[g] = sg * (1.f - (float)tmask[g]);
      }
    }
  }
}

// ---------------- Group sums (batch sorted) ----------------
__global__ void k_grpsum(const float* __restrict__ pi, const float* __restrict__ c_cost,
                         const int* __restrict__ batch, float* __restrict__ exp_tot, int N) {
  __shared__ float lsf[256];
  __shared__ int lsi[256];
  int t = threadIdx.x;
  int i = blockIdx.x * TPB + t;
  bool valid = i < N;
  int g = valid ? batch[i] : 0;
  float v = valid ? pi[i] * c_cost[i] : 0.f;
  lsi[t] = valid ? g : 0x7fffffff;
  __syncthreads();
  for (int s = 128; s > 0; s >>= 1) { if (t < s) lsi[t] = min(lsi[t], lsi[t + s]); __syncthreads(); }
  int gmin = lsi[0];
  __syncthreads();
  lsi[t] = valid ? g : -1;
  __syncthreads();
  for (int s = 128; s > 0; s >>= 1) { if (t < s) lsi[t] = max(lsi[t], lsi[t + s]); __syncthreads(); }
  int gmax = lsi[0];
  __syncthreads();
  for (int gg = gmin; gg <= gmax; ++gg) {
    lsf[t] = (valid && g == gg) ? v : 0.f;
    __syncthreads();
    for (int s = 128; s > 0; s >>= 1) { if (t < s) lsf[t] += lsf[t + s]; __syncthreads(); }
    if (t == 0) atomicAdd(&exp_tot[gg], lsf[0]);
    __syncthreads();
  }
}

__global__ void k_final(const float* __restrict__ pi, const int* __restrict__ batch,
                        const float* __restrict__ B_total, const float* __restrict__ exp_tot,
                        float* __restrict__ out, int N) {
  int i = blockIdx.x * TPB + threadIdx.x;
  if (i < N) {
    int g = batch[i];
    float ratio = fminf(B_total[g] / (exp_tot[g] + 1e-12f), 1.f);
    out[i] = pi[i] * ratio;
  }
}

extern "C" void kernel_launch(void* const* d_in, const int* in_sizes, int n_in,
                              void* d_out, int out_size, void* d_ws, size_t ws_size,
                              hipStream_t stream) {
  const float* x     = (const float*)d_in[0];
  const int*   ei    = (const int*)d_in[1];
  const float* eattr = (const float*)d_in[2];
  const int*   batch = (const int*)d_in[3];
  const float* Btot  = (const float*)d_in[4];
  const int*   tmask = (const int*)d_in[5];
  const float* ccost = (const float*)d_in[6];
  const float* We1 = (const float*)d_in[7],  *be1 = (const float*)d_in[8];
  const float* W1a = (const float*)d_in[9],  *b1a = (const float*)d_in[10];
  const float* W1b = (const float*)d_in[11], *b1b = (const float*)d_in[12];
  const float* We2 = (const float*)d_in[13], *be2 = (const float*)d_in[14];
  const float* W2a = (const float*)d_in[15], *b2a = (const float*)d_in[16];
  const float* W2b = (const float*)d_in[17], *b2b = (const float*)d_in[18];
  const float* Wr1 = (const float*)d_in[19], *br1 = (const float*)d_in[20];
  const float* Wr2 = (const float*)d_in[21], *br2 = (const float*)d_in[22];
  float* out = (float*)d_out;

  const int N = in_sizes[0] / 9;
  const int E = in_sizes[2];
  const int G = in_sizes[4];
  const int* src = ei;
  const int* dst = ei + E;
  const int B = (N + (1 << BSHIFT) - 1) >> BSHIFT;  // 256-node bins
  const int nscan = B * P_BLOCKS;

  // workspace carve-up (4-byte elements)
  size_t cur = 0;
  auto alloc = [&](size_t elems) { size_t r = cur; cur += elems; cur = (cur + 63) & ~(size_t)63; return r; };
  char* wsb = (char*)d_ws;
  size_t o_exp    = alloc(G);             // zeroed
  size_t o_counts = alloc(nscan);
  size_t o_offs   = alloc(nscan + 1);
  size_t o_bsums  = alloc(256);
  size_t o_noffs  = alloc(N + 1);
  size_t o_csr    = alloc(2 * (size_t)E);
  size_t e_or_h   = (2 * (size_t)E > (size_t)N * 32) ? 2 * (size_t)E : (size_t)N * 32;
  size_t o_ebuf   = alloc(e_or_h);        // ebuf (dead after k_bsort) aliased with h1 (fp16)
  size_t o_u1     = alloc((size_t)N * 9);
  size_t o_u2     = alloc((size_t)N * 64);
  size_t o_pi     = alloc(N);
  (void)ws_size;

  float* exp_t  = (float*)wsb + o_exp;
  int*   counts = (int*)wsb + o_counts;
  int*   offs   = (int*)wsb + o_offs;
  int*   bsums  = (int*)wsb + o_bsums;
  int*   noffs  = (int*)wsb + o_noffs;
  int2*  csr    = (int2*)((int*)wsb + o_csr);
  int2*  ebuf   = (int2*)((int*)wsb + o_ebuf);
  __half* h1h   = (__half*)((int*)wsb + o_ebuf);  // alias: ebuf dead before h1 written
  float* u1     = (float*)wsb + o_u1;
  float* u2     = (float*)wsb + o_u2;
  float* pi     = (float*)wsb + o_pi;

  (void)hipMemsetAsync(exp_t, 0, (size_t)G * 4, stream);

  const int nb = (nscan + 1023) / 1024;

  k_bhist<<<P_BLOCKS, TPB, 0, stream>>>(dst, counts, E, B);
  k_scan_block<<<nb, TPB, 0, stream>>>(counts, offs, bsums, nscan);
  k_scan_mid<<<1, 256, 0, stream>>>(bsums, nb);
  k_scan_add<<<nb, TPB, 0, stream>>>(offs, bsums, nscan, E);
  k_bfill<<<P_BLOCKS, TPB, 0, stream>>>(src, dst, eattr, offs, ebuf, E, B);
  k_bsort<<<B, TPB, 0, stream>>>((const long long*)ebuf, offs, csr, noffs, N, E);

  k_agg1<<<((size_t)N * 16 + TPB - 1) / TPB, TPB, 0, stream>>>(x, csr, noffs, We1, be1, u1, N);
  k_mlp<9, true><<<(N + 63) / 64, TPB, 0, stream>>>(u1, W1a, b1a, W1b, b1b, (void*)h1h, N);

  k_agg2<<<((size_t)N * 64 + TPB - 1) / TPB, TPB, 0, stream>>>(h1h, csr, noffs, We2, be2, u2, N);
  k_mlp<64, false><<<(N + 63) / 64, TPB, 0, stream>>>(u2, W2a, b2a, W2b, b2b, (void*)u2, N);

  k_readout<<<(N + 31) / 32, TPB, 0, stream>>>(u2, Wr1, br1, Wr2, br2, tmask, pi, N);
  k_grpsum<<<(N + TPB - 1) / TPB, TPB, 0, stream>>>(pi, ccost, batch, exp_t, N);
  k_final<<<(N + TPB - 1) / TPB, TPB, 0, stream>>>(pi, batch, Btot, exp_t, out, N);
}

// Round 7
// 487.416 us; speedup vs baseline: 3.5551x; 1.0015x over previous
//
#include <hip/hip_runtime.h>
#include <hip/hip_fp16.h>
#include <math.h>

#define TPB 256
#define P_BLOCKS 512
#define BSHIFT 8          // 256 nodes per bin
#define BINS_MAX 512      // >= ceil(100000/256)=391

struct alignas(8)  h2x2 { __half2 a, b; };
struct alignas(16) h2x4 { __half2 a, b, c, d; };

// ---------------- bucketed histogram: counts[bin*P + blk] ----------------
__global__ void __launch_bounds__(256) k_bhist(const int* __restrict__ dst,
                                               int* __restrict__ counts, int E, int B) {
  __shared__ int h[BINS_MAX];
  int t = threadIdx.x, blk = blockIdx.x;
  for (int i = t; i < B; i += TPB) h[i] = 0;
  __syncthreads();
  int chunk = (E + P_BLOCKS - 1) / P_BLOCKS;
  int s = blk * chunk, e = min(E, s + chunk);
  for (int i = s + t; i < e; i += TPB)
    atomicAdd(&h[__builtin_nontemporal_load(&dst[i]) >> BSHIFT], 1);
  __syncthreads();
  for (int i = t; i < B; i += TPB) counts[i * P_BLOCKS + blk] = h[i];
}

// ---------------- scan (1024 items/block) ----------------
__global__ void k_scan_block(const int* __restrict__ deg, int* __restrict__ offs,
                             int* __restrict__ bsums, int n) {
  __shared__ int lds[256];
  int t = threadIdx.x, b = blockIdx.x;
  int base = b * 1024 + t * 4;
  int v0 = (base + 0 < n) ? deg[base + 0] : 0;
  int v1 = (base + 1 < n) ? deg[base + 1] : 0;
  int v2 = (base + 2 < n) ? deg[base + 2] : 0;
  int v3 = (base + 3 < n) ? deg[base + 3] : 0;
  int s = v0 + v1 + v2 + v3;
  lds[t] = s;
  __syncthreads();
  int acc = s;
  for (int off = 1; off < 256; off <<= 1) {
    int x = (t >= off) ? lds[t - off] : 0;
    __syncthreads();
    acc += x;
    lds[t] = acc;
    __syncthreads();
  }
  int excl = acc - s;
  if (base + 0 < n) offs[base + 0] = excl;
  if (base + 1 < n) offs[base + 1] = excl + v0;
  if (base + 2 < n) offs[base + 2] = excl + v0 + v1;
  if (base + 3 < n) offs[base + 3] = excl + v0 + v1 + v2;
  if (t == 255) bsums[b] = acc;
}

__global__ void k_scan_mid(int* __restrict__ bsums, int nb) {
  __shared__ int lds[256];
  int t = threadIdx.x;
  int v = (t < nb) ? bsums[t] : 0;
  lds[t] = v;
  __syncthreads();
  int acc = v;
  for (int off = 1; off < 256; off <<= 1) {
    int x = (t >= off) ? lds[t - off] : 0;
    __syncthreads();
    acc += x;
    lds[t] = acc;
    __syncthreads();
  }
  if (t < nb) bsums[t] = acc - v;  // exclusive
}

__global__ void k_scan_add(int* __restrict__ offs, const int* __restrict__ bsums,
                           int n, int total) {
  int t = threadIdx.x, b = blockIdx.x;
  int add = bsums[b];
  int base = b * 1024 + t * 4;
#pragma unroll
  for (int j = 0; j < 4; ++j)
    if (base + j < n) offs[base + j] += add;
  if (b == 0 && t == 0) offs[n] = total;
}

// ---------------- fill: atomic-free (LDS cursors), streaming bin appends ----------------
__global__ void __launch_bounds__(256) k_bfill(const int* __restrict__ src,
                                               const int* __restrict__ dst,
                                               const float* __restrict__ attr,
                                               const int* __restrict__ offs,
                                               int2* __restrict__ ebuf, int E, int B) {
  __shared__ int cur[BINS_MAX];
  int t = threadIdx.x, blk = blockIdx.x;
  for (int i = t; i < B; i += TPB) cur[i] = offs[i * P_BLOCKS + blk];
  __syncthreads();
  int chunk = (E + P_BLOCKS - 1) / P_BLOCKS;
  int s = blk * chunk, e = min(E, s + chunk);
#pragma unroll 4
  for (int i = s + t; i < e; i += TPB) {
    int d = __builtin_nontemporal_load(&dst[i]);
    int sv = __builtin_nontemporal_load(&src[i]);
    float av = __builtin_nontemporal_load(&attr[i]);
    int bin = d >> BSHIFT;
    int pos = atomicAdd(&cur[bin], 1);
    ebuf[pos] = make_int2((sv << BSHIFT) | (d & ((1 << BSHIFT) - 1)), __float_as_int(av));
  }
}

// ---------------- per-bin counting sort -> dst-sorted csr + node offsets ----------------
__global__ void __launch_bounds__(256) k_bsort(const long long* __restrict__ ebuf,
                                               const int* __restrict__ offs,
                                               int2* __restrict__ csr,
                                               int* __restrict__ noffs,
                                               int N, int E) {
  __shared__ int hist[256];
  __shared__ int cursor[256];
  __shared__ int sc[256];
  int t = threadIdx.x, bkt = blockIdx.x;
  hist[t] = 0;
  __syncthreads();
  int s = offs[bkt * P_BLOCKS], e = offs[(bkt + 1) * P_BLOCKS];
#pragma unroll 4
  for (int i = s + t; i < e; i += TPB) {
    long long pv = __builtin_nontemporal_load(&ebuf[i]);
    int key = (int)(unsigned int)(pv & 0xffffffffLL);
    atomicAdd(&hist[key & 255], 1);
  }
  __syncthreads();
  int v = hist[t];
  int acc = v;
  sc[t] = v;
  __syncthreads();
  for (int off = 1; off < 256; off <<= 1) {
    int x = (t >= off) ? sc[t - off] : 0;
    __syncthreads();
    acc += x;
    sc[t] = acc;
    __syncthreads();
  }
  int base = s + acc - v;  // exclusive within bucket
  cursor[t] = base;
  int n = (bkt << BSHIFT) + t;
  if (n < N) noffs[n] = base;
  if (bkt == 0 && t == 0) noffs[N] = E;
  __syncthreads();
#pragma unroll 4
  for (int i = s + t; i < e; i += TPB) {
    long long pv = __builtin_nontemporal_load(&ebuf[i]);
    int key = (int)(unsigned int)(pv & 0xffffffffLL);
    int attr = (int)(unsigned int)(((unsigned long long)pv) >> 32);
    int pos = atomicAdd(&cursor[key & 255], 1);
    csr[pos] = make_int2(((unsigned int)key) >> BSHIFT, attr);
  }
}

// ---------------- Layer-1 aggregation: 16 threads/node, f<9 active ----------------
__global__ void __launch_bounds__(256) k_agg1(
    const float* __restrict__ x, const int2* __restrict__ csr,
    const int* __restrict__ noffs, const float* __restrict__ We1,
    const float* __restrict__ be1, float* __restrict__ u1, int N) {
  int t = blockIdx.x * TPB + threadIdx.x;
  int node = t >> 4, f = t & 15;
  if (node >= N || f >= 9) return;
  int o0 = noffs[node], o1 = noffs[node + 1];
  float we = We1[f], be = be1[f];
  float acc = 0.f;
  int e = o0;
  for (; e + 3 < o1; e += 4) {
    int2 p0 = csr[e], p1 = csr[e + 1], p2 = csr[e + 2], p3 = csr[e + 3];
    float v0 = x[p0.x * 9 + f] + fmaf(__int_as_float(p0.y), we, be);
    float v1 = x[p1.x * 9 + f] + fmaf(__int_as_float(p1.y), we, be);
    float v2 = x[p2.x * 9 + f] + fmaf(__int_as_float(p2.y), we, be);
    float v3 = x[p3.x * 9 + f] + fmaf(__int_as_float(p3.y), we, be);
    acc += fmaxf(v0, 0.f) + fmaxf(v1, 0.f) + fmaxf(v2, 0.f) + fmaxf(v3, 0.f);
  }
  for (; e < o1; ++e) {
    int2 p = csr[e];
    acc += fmaxf(x[p.x * 9 + f] + fmaf(__int_as_float(p.y), we, be), 0.f);
  }
  u1[node * 9 + f] = x[node * 9 + f] + acc;
}

// ---------------- Layer-2 aggregation: one wave/node; 8 edge-slots x 8 feature-chunks ----------------
// lane = (q,c): q=lane>>3 edge slot, c=lane&7 features c*8..c*8+7 (16B gather per lane).
// Main loop: 32 edges/iter -> 4 csr loads + 4 16B gathers in flight per lane.
__global__ void __launch_bounds__(256) k_agg2(
    const __half* __restrict__ h1, const long long* __restrict__ csr,
    const int* __restrict__ noffs, const float* __restrict__ We2,
    const float* __restrict__ be2, float* __restrict__ u2, int N) {
  int gt = blockIdx.x * TPB + threadIdx.x;
  int node = gt >> 6;
  if (node >= N) return;
  int lane = gt & 63;
  int q = lane >> 3, c = lane & 7;
  float4 weA = *(const float4*)&We2[c * 8];
  float4 weB = *(const float4*)&We2[c * 8 + 4];
  float4 beA = *(const float4*)&be2[c * 8];
  float4 beB = *(const float4*)&be2[c * 8 + 4];
  int o0 = noffs[node], o1 = noffs[node + 1];
  float a0 = 0.f, a1 = 0.f, a2 = 0.f, a3 = 0.f, a4 = 0.f, a5 = 0.f, a6 = 0.f, a7 = 0.f;

#define AGG2_ACC(pv, v)                                                      \
  {                                                                          \
    float ea = __int_as_float((int)(unsigned int)(((unsigned long long)(pv)) >> 32)); \
    float2 f0 = __half22float2((v).a), f1 = __half22float2((v).b);           \
    float2 f2 = __half22float2((v).c), f3 = __half22float2((v).d);           \
    a0 += fmaxf(f0.x + fmaf(ea, weA.x, beA.x), 0.f);                         \
    a1 += fmaxf(f0.y + fmaf(ea, weA.y, beA.y), 0.f);                         \
    a2 += fmaxf(f1.x + fmaf(ea, weA.z, beA.z), 0.f);                         \
    a3 += fmaxf(f1.y + fmaf(ea, weA.w, beA.w), 0.f);                         \
    a4 += fmaxf(f2.x + fmaf(ea, weB.x, beB.x), 0.f);                         \
    a5 += fmaxf(f2.y + fmaf(ea, weB.y, beB.y), 0.f);                         \
    a6 += fmaxf(f3.x + fmaf(ea, weB.z, beB.z), 0.f);                         \
    a7 += fmaxf(f3.y + fmaf(ea, weB.w, beB.w), 0.f);                         \
  }

  int e = o0;
  for (; e + 32 <= o1; e += 32) {
    long long pv0 = __builtin_nontemporal_load(&csr[e + q]);
    long long pv1 = __builtin_nontemporal_load(&csr[e + 8 + q]);
    long long pv2 = __builtin_nontemporal_load(&csr[e + 16 + q]);
    long long pv3 = __builtin_nontemporal_load(&csr[e + 24 + q]);
    h2x4 v0 = *(const h2x4*)(h1 + (size_t)(int)(unsigned int)(pv0 & 0xffffffffLL) * 64 + c * 8);
    h2x4 v1 = *(const h2x4*)(h1 + (size_t)(int)(unsigned int)(pv1 & 0xffffffffLL) * 64 + c * 8);
    h2x4 v2 = *(const h2x4*)(h1 + (size_t)(int)(unsigned int)(pv2 & 0xffffffffLL) * 64 + c * 8);
    h2x4 v3 = *(const h2x4*)(h1 + (size_t)(int)(unsigned int)(pv3 & 0xffffffffLL) * 64 + c * 8);
    AGG2_ACC(pv0, v0); AGG2_ACC(pv1, v1); AGG2_ACC(pv2, v2); AGG2_ACC(pv3, v3);
  }
  for (; e < o1; e += 8) {
    if (e + q < o1) {
      long long pv = __builtin_nontemporal_load(&csr[e + q]);
      h2x4 v = *(const h2x4*)(h1 + (size_t)(int)(unsigned int)(pv & 0xffffffffLL) * 64 + c * 8);
      AGG2_ACC(pv, v);
    }
  }
#undef AGG2_ACC

  a0 += __shfl_xor(a0, 8, 64); a0 += __shfl_xor(a0, 16, 64); a0 += __shfl_xor(a0, 32, 64);
  a1 += __shfl_xor(a1, 8, 64); a1 += __shfl_xor(a1, 16, 64); a1 += __shfl_xor(a1, 32, 64);
  a2 += __shfl_xor(a2, 8, 64); a2 += __shfl_xor(a2, 16, 64); a2 += __shfl_xor(a2, 32, 64);
  a3 += __shfl_xor(a3, 8, 64); a3 += __shfl_xor(a3, 16, 64); a3 += __shfl_xor(a3, 32, 64);
  a4 += __shfl_xor(a4, 8, 64); a4 += __shfl_xor(a4, 16, 64); a4 += __shfl_xor(a4, 32, 64);
  a5 += __shfl_xor(a5, 8, 64); a5 += __shfl_xor(a5, 16, 64); a5 += __shfl_xor(a5, 32, 64);
  a6 += __shfl_xor(a6, 8, 64); a6 += __shfl_xor(a6, 16, 64); a6 += __shfl_xor(a6, 32, 64);
  a7 += __shfl_xor(a7, 8, 64); a7 += __shfl_xor(a7, 16, 64); a7 += __shfl_xor(a7, 32, 64);

  if (q == 0) {
    h2x4 sf = *(const h2x4*)(h1 + (size_t)node * 64 + c * 8);
    float2 s0 = __half22float2(sf.a), s1 = __half22float2(sf.b);
    float2 s2 = __half22float2(sf.c), s3 = __half22float2(sf.d);
    float4 oA, oB;
    oA.x = s0.x + a0; oA.y = s0.y + a1; oA.z = s1.x + a2; oA.w = s1.y + a3;
    oB.x = s2.x + a4; oB.y = s2.y + a5; oB.z = s3.x + a6; oB.w = s3.y + a7;
    *(float4*)&u2[(size_t)node * 64 + c * 8] = oA;
    *(float4*)&u2[(size_t)node * 64 + c * 8 + 4] = oB;
  }
}

// ---------------- Layer-1 MLP (9->64->64), fp16 output ----------------
__global__ void __launch_bounds__(256) k_mlp9(
    const float* __restrict__ uin, const float* __restrict__ Wa,
    const float* __restrict__ ba, const float* __restrict__ Wb,
    const float* __restrict__ bb, __half* __restrict__ hout, int N) {
  constexpr int KIN = 9;
  __shared__ float ls_in[64 * KIN];
  __shared__ float ls_z[64 * 65];
  __shared__ float ls_w[64 * 64];
  __shared__ float ls_b[128];
  const int t = threadIdx.x;
  const int n0 = blockIdx.x * 64;

  for (int i = t; i < 64 * KIN; i += TPB) {
    int r = i / KIN, c = i % KIN;
    int g = n0 + r;
    ls_in[i] = (g < N) ? uin[g * KIN + c] : 0.f;
  }
  for (int i = t; i < KIN * 64; i += TPB) ls_w[i] = Wa[i];
  if (t < 64) { ls_b[t] = ba[t]; ls_b[64 + t] = bb[t]; }
  __syncthreads();

  const int of = (t & 15) * 4, nb = (t >> 4) * 4;
  float acc[4][4];
#pragma unroll
  for (int i = 0; i < 4; ++i)
#pragma unroll
    for (int j = 0; j < 4; ++j) acc[i][j] = 0.f;

  for (int k = 0; k < KIN; ++k) {
    float4 w = *(const float4*)&ls_w[k * 64 + of];
#pragma unroll
    for (int ni = 0; ni < 4; ++ni) {
      float uv = ls_in[(nb + ni) * KIN + k];
      acc[ni][0] += uv * w.x; acc[ni][1] += uv * w.y;
      acc[ni][2] += uv * w.z; acc[ni][3] += uv * w.w;
    }
  }
#pragma unroll
  for (int ni = 0; ni < 4; ++ni)
#pragma unroll
    for (int oi = 0; oi < 4; ++oi)
      ls_z[(nb + ni) * 65 + of + oi] = fmaxf(acc[ni][oi] + ls_b[of + oi], 0.f);
  __syncthreads();
  for (int i = t; i < 4096; i += TPB) ls_w[i] = Wb[i];
  __syncthreads();

#pragma unroll
  for (int i = 0; i < 4; ++i)
#pragma unroll
    for (int j = 0; j < 4; ++j) acc[i][j] = 0.f;
  for (int k = 0; k < 64; ++k) {
    float4 w = *(const float4*)&ls_w[k * 64 + of];
#pragma unroll
    for (int ni = 0; ni < 4; ++ni) {
      float zv = ls_z[(nb + ni) * 65 + k];
      acc[ni][0] += zv * w.x; acc[ni][1] += zv * w.y;
      acc[ni][2] += zv * w.z; acc[ni][3] += zv * w.w;
    }
  }
#pragma unroll
  for (int ni = 0; ni < 4; ++ni) {
    int n = n0 + nb + ni;
    if (n < N) {
      float ox = fmaxf(acc[ni][0] + ls_b[64 + of + 0], 0.f);
      float oy = fmaxf(acc[ni][1] + ls_b[64 + of + 1], 0.f);
      float oz = fmaxf(acc[ni][2] + ls_b[64 + of + 2], 0.f);
      float ow = fmaxf(acc[ni][3] + ls_b[64 + of + 3], 0.f);
      h2x2 hv;
      hv.a = __float22half2_rn(make_float2(ox, oy));
      hv.b = __float22half2_rn(make_float2(oz, ow));
      *(h2x2*)(hout + (size_t)n * 64 + of) = hv;
    }
  }
}

// ---------------- Layer-2 MLP (64->64->64) fused with readout -> pi ----------------
__global__ void __launch_bounds__(256) k_mlp_ro(
    const float* __restrict__ uin, const float* __restrict__ Wa,
    const float* __restrict__ ba, const float* __restrict__ Wb,
    const float* __restrict__ bb, const float* __restrict__ Wr1,
    const float* __restrict__ br1, const float* __restrict__ Wr2,
    const float* __restrict__ br2, const int* __restrict__ tmask,
    float* __restrict__ pi, int N) {
  __shared__ float ls_in[64 * 65];
  __shared__ float ls_z[64 * 65];
  __shared__ float ls_w[64 * 64];
  __shared__ float ls_b[128];
  __shared__ float ls_w2[32];
  __shared__ float ls_b1[32];
  const int t = threadIdx.x;
  const int n0 = blockIdx.x * 64;

  for (int i = t; i < 64 * 64; i += TPB) {
    int r = i >> 6, c = i & 63;
    int g = n0 + r;
    ls_in[r * 65 + c] = (g < N) ? uin[(size_t)g * 64 + c] : 0.f;
  }
  for (int i = t; i < 4096; i += TPB) ls_w[i] = Wa[i];
  if (t < 64) { ls_b[t] = ba[t]; ls_b[64 + t] = bb[t]; }
  __syncthreads();

  const int of = (t & 15) * 4, nb = (t >> 4) * 4;
  float acc[4][4];
#pragma unroll
  for (int i = 0; i < 4; ++i)
#pragma unroll
    for (int j = 0; j < 4; ++j) acc[i][j] = 0.f;
  for (int k = 0; k < 64; ++k) {
    float4 w = *(const float4*)&ls_w[k * 64 + of];
#pragma unroll
    for (int ni = 0; ni < 4; ++ni) {
      float uv = ls_in[(nb + ni) * 65 + k];
      acc[ni][0] += uv * w.x; acc[ni][1] += uv * w.y;
      acc[ni][2] += uv * w.z; acc[ni][3] += uv * w.w;
    }
  }
#pragma unroll
  for (int ni = 0; ni < 4; ++ni)
#pragma unroll
    for (int oi = 0; oi < 4; ++oi)
      ls_z[(nb + ni) * 65 + of + oi] = fmaxf(acc[ni][oi] + ls_b[of + oi], 0.f);
  __syncthreads();
  for (int i = t; i < 4096; i += TPB) ls_w[i] = Wb[i];
  __syncthreads();

#pragma unroll
  for (int i = 0; i < 4; ++i)
#pragma unroll
    for (int j = 0; j < 4; ++j) acc[i][j] = 0.f;
  for (int k = 0; k < 64; ++k) {
    float4 w = *(const float4*)&ls_w[k * 64 + of];
#pragma unroll
    for (int ni = 0; ni < 4; ++ni) {
      float zv = ls_z[(nb + ni) * 65 + k];
      acc[ni][0] += zv * w.x; acc[ni][1] += zv * w.y;
      acc[ni][2] += zv * w.z; acc[ni][3] += zv * w.w;
    }
  }
  // h2 stays in LDS (reuse ls_in)
#pragma unroll
  for (int ni = 0; ni < 4; ++ni)
#pragma unroll
    for (int oi = 0; oi < 4; ++oi)
      ls_in[(nb + ni) * 65 + of + oi] = fmaxf(acc[ni][oi] + ls_b[64 + of + oi], 0.f);
  __syncthreads();
  for (int i = t; i < 2048; i += TPB) ls_w[i] = Wr1[i];
  if (t < 32) { ls_w2[t] = Wr2[t]; ls_b1[t] = br1[t]; }
  __syncthreads();

  int of32 = t & 31, q8 = t >> 5;
  float b2 = br2[0];
#pragma unroll
  for (int j = 0; j < 8; ++j) {
    int n = q8 * 8 + j;
    float a = 0.f;
    for (int k = 0; k < 64; ++k) a += ls_in[n * 65 + k] * ls_w[k * 32 + of32];
    float r = fmaxf(a + ls_b1[of32], 0.f) * ls_w2[of32];
    for (int s = 16; s > 0; s >>= 1) r += __shfl_down(r, s, 32);
    if (of32 == 0) {
      int g = n0 + n;
      if (g < N) {
        float sg = 1.f / (1.f + expf(-(r + b2)));
        pi[g] = sg * (1.f - (float)tmask[g]);
      }
    }
  }
}

// ---------------- Group sums (batch sorted) ----------------
__global__ void k_grpsum(const float* __restrict__ pi, const float* __restrict__ c_cost,
                         const int* __restrict__ batch, float* __restrict__ exp_tot, int N) {
  __shared__ float lsf[256];
  __shared__ int lsi[256];
  int t = threadIdx.x;
  int i = blockIdx.x * TPB + t;
  bool valid = i < N;
  int g = valid ? batch[i] : 0;
  float v = valid ? pi[i] * c_cost[i] : 0.f;
  lsi[t] = valid ? g : 0x7fffffff;
  __syncthreads();
  for (int s = 128; s > 0; s >>= 1) { if (t < s) lsi[t] = min(lsi[t], lsi[t + s]); __syncthreads(); }
  int gmin = lsi[0];
  __syncthreads();
  lsi[t] = valid ? g : -1;
  __syncthreads();
  for (int s = 128; s > 0; s >>= 1) { if (t < s) lsi[t] = max(lsi[t], lsi[t + s]); __syncthreads(); }
  int gmax = lsi[0];
  __syncthreads();
  for (int gg = gmin; gg <= gmax; ++gg) {
    lsf[t] = (valid && g == gg) ? v : 0.f;
    __syncthreads();
    for (int s = 128; s > 0; s >>= 1) { if (t < s) lsf[t] += lsf[t + s]; __syncthreads(); }
    if (t == 0) atomicAdd(&exp_tot[gg], lsf[0]);
    __syncthreads();
  }
}

__global__ void k_final(const float* __restrict__ pi, const int* __restrict__ batch,
                        const float* __restrict__ B_total, const float* __restrict__ exp_tot,
                        float* __restrict__ out, int N) {
  int i = blockIdx.x * TPB + threadIdx.x;
  if (i < N) {
    int g = batch[i];
    float ratio = fminf(B_total[g] / (exp_tot[g] + 1e-12f), 1.f);
    out[i] = pi[i] * ratio;
  }
}

extern "C" void kernel_launch(void* const* d_in, const int* in_sizes, int n_in,
                              void* d_out, int out_size, void* d_ws, size_t ws_size,
                              hipStream_t stream) {
  const float* x     = (const float*)d_in[0];
  const int*   ei    = (const int*)d_in[1];
  const float* eattr = (const float*)d_in[2];
  const int*   batch = (const int*)d_in[3];
  const float* Btot  = (const float*)d_in[4];
  const int*   tmask = (const int*)d_in[5];
  const float* ccost = (const float*)d_in[6];
  const float* We1 = (const float*)d_in[7],  *be1 = (const float*)d_in[8];
  const float* W1a = (const float*)d_in[9],  *b1a = (const float*)d_in[10];
  const float* W1b = (const float*)d_in[11], *b1b = (const float*)d_in[12];
  const float* We2 = (const float*)d_in[13], *be2 = (const float*)d_in[14];
  const float* W2a = (const float*)d_in[15], *b2a = (const float*)d_in[16];
  const float* W2b = (const float*)d_in[17], *b2b = (const float*)d_in[18];
  const float* Wr1 = (const float*)d_in[19], *br1 = (const float*)d_in[20];
  const float* Wr2 = (const float*)d_in[21], *br2 = (const float*)d_in[22];
  float* out = (float*)d_out;

  const int N = in_sizes[0] / 9;
  const int E = in_sizes[2];
  const int G = in_sizes[4];
  const int* src = ei;
  const int* dst = ei + E;
  const int B = (N + (1 << BSHIFT) - 1) >> BSHIFT;  // 256-node bins
  const int nscan = B * P_BLOCKS;

  // workspace carve-up (4-byte elements)
  size_t cur = 0;
  auto alloc = [&](size_t elems) { size_t r = cur; cur += elems; cur = (cur + 63) & ~(size_t)63; return r; };
  char* wsb = (char*)d_ws;
  size_t o_exp    = alloc(G);             // zeroed
  size_t o_counts = alloc(nscan);
  size_t o_offs   = alloc(nscan + 1);
  size_t o_bsums  = alloc(256);
  size_t o_noffs  = alloc(N + 1);
  size_t o_csr    = alloc(2 * (size_t)E);
  size_t e_or_h   = (2 * (size_t)E > (size_t)N * 32) ? 2 * (size_t)E : (size_t)N * 32;
  size_t o_ebuf   = alloc(e_or_h);        // ebuf (dead after k_bsort) aliased with h1 (fp16)
  size_t o_u1     = alloc((size_t)N * 9);
  size_t o_u2     = alloc((size_t)N * 64);
  size_t o_pi     = alloc(N);
  (void)ws_size;

  float* exp_t  = (float*)wsb + o_exp;
  int*   counts = (int*)wsb + o_counts;
  int*   offs   = (int*)wsb + o_offs;
  int*   bsums  = (int*)wsb + o_bsums;
  int*   noffs  = (int*)wsb + o_noffs;
  int2*  csr    = (int2*)((int*)wsb + o_csr);
  int2*  ebuf   = (int2*)((int*)wsb + o_ebuf);
  __half* h1h   = (__half*)((int*)wsb + o_ebuf);  // alias: ebuf dead before h1 written
  float* u1     = (float*)wsb + o_u1;
  float* u2     = (float*)wsb + o_u2;
  float* pi     = (float*)wsb + o_pi;

  (void)hipMemsetAsync(exp_t, 0, (size_t)G * 4, stream);

  const int nb = (nscan + 1023) / 1024;

  k_bhist<<<P_BLOCKS, TPB, 0, stream>>>(dst, counts, E, B);
  k_scan_block<<<nb, TPB, 0, stream>>>(counts, offs, bsums, nscan);
  k_scan_mid<<<1, 256, 0, stream>>>(bsums, nb);
  k_scan_add<<<nb, TPB, 0, stream>>>(offs, bsums, nscan, E);
  k_bfill<<<P_BLOCKS, TPB, 0, stream>>>(src, dst, eattr, offs, ebuf, E, B);
  k_bsort<<<B, TPB, 0, stream>>>((const long long*)ebuf, offs, csr, noffs, N, E);

  k_agg1<<<((size_t)N * 16 + TPB - 1) / TPB, TPB, 0, stream>>>(x, csr, noffs, We1, be1, u1, N);
  k_mlp9<<<(N + 63) / 64, TPB, 0, stream>>>(u1, W1a, b1a, W1b, b1b, h1h, N);

  k_agg2<<<((size_t)N * 64 + TPB - 1) / TPB, TPB, 0, stream>>>(h1h, (const long long*)csr, noffs, We2, be2, u2, N);
  k_mlp_ro<<<(N + 63) / 64, TPB, 0, stream>>>(u2, W2a, b2a, W2b, b2b, Wr1, br1, Wr2, br2, tmask, pi, N);

  k_grpsum<<<(N + TPB - 1) / TPB, TPB, 0, stream>>>(pi, ccost, batch, exp_t, N);
  k_final<<<(N + TPB - 1) / TPB, TPB, 0, stream>>>(pi, batch, Btot, exp_t, out, N);
}